// Round 7
// baseline (467.755 us; speedup 1.0000x reference)
//
#include <hip/hip_runtime.h>
#include <hip/hip_bf16.h>
#include <math.h>

typedef unsigned short ushort_t;
typedef short bf16x8 __attribute__((ext_vector_type(8)));
typedef float f32x4 __attribute__((ext_vector_type(4)));

#define NNODES   8192
#define DIN      768
#define DSTRUCT  32
#define XDIM     800
#define DHID     768
#define DOUT     768
#define MEMK     64
#define NGRAPH   64
#define BUCKET_CAP 128

// ---------------- workspace layout (bytes) ----------------
#define OFF_XHI     0u
#define OFF_XLO     (OFF_XHI  + 8192u*800u*2u)
#define OFF_HHI     (OFF_XLO  + 8192u*800u*2u)
#define OFF_HLO     (OFF_HHI  + 8192u*768u*2u)
#define OFF_NF      (OFF_HLO  + 8192u*768u*2u)     // f32 [8192][768]
#define OFF_NFHI    (OFF_NF   + 8192u*768u*4u)
#define OFF_NFLO    (OFF_NFHI + 8192u*768u*2u)
#define OFF_W1THI   (OFF_NFLO + 8192u*768u*2u)
#define OFF_W1TLO   (OFF_W1THI + 768u*800u*2u)
#define OFF_W2THI   (OFF_W1TLO + 768u*800u*2u)
#define OFF_W2TLO   (OFF_W2THI + 768u*768u*2u)
#define OFF_MHI     (OFF_W2TLO + 768u*768u*2u)
#define OFF_MLO     (OFF_MHI  + 64u*768u*2u)
#define OFF_MTHI    (OFF_MLO  + 64u*768u*2u)
#define OFF_MTLO    (OFF_MTHI + 768u*64u*2u)
#define OFF_BUCKET  (OFF_MTLO + 768u*64u*2u)
#define OFF_COUNTS  (OFF_BUCKET + 8192u*BUCKET_CAP*4u)
#define OFF_GSTART  (OFF_COUNTS + 8192u*4u)
#define OFF_GEND    (OFF_GSTART + 256u)
#define OFF_LOSS    (OFF_GEND + 256u)
#define OFF_GFEAT   (OFF_LOSS + 256u)          // gfeatT [768][64] f32
#define OFF_T1      (OFF_GFEAT + 768u*64u*4u)  // t1T [768][64] f32
#define ZERO_OFF    OFF_COUNTS
#define ZERO_BYTES  (8192u*4u + 256u + 256u + 256u)

// ---------------- helpers ----------------
__device__ __forceinline__ ushort_t bf_rne(float f) {
    unsigned u = __float_as_uint(f);
    return (ushort_t)((u + 0x7FFFu + ((u >> 16) & 1u)) >> 16);
}
__device__ __forceinline__ void split_bf16(float f, ushort_t& hi, ushort_t& lo) {
    ushort_t h = bf_rne(f);
    float fh = __uint_as_float(((unsigned)h) << 16);
    hi = h;
    lo = bf_rne(f - fh);
}
__device__ __forceinline__ void gld16(const void* g, void* l) {
    __builtin_amdgcn_global_load_lds(
        (const __attribute__((address_space(1))) unsigned int*)g,
        (__attribute__((address_space(3))) unsigned int*)l, 16, 0, 0);
}

// ---------------- fused prep: transpose+split W1/W2/mem, split mem ----------------
__device__ __forceinline__ void dsplit(const float* __restrict__ W,
                                       ushort_t* __restrict__ Thi, ushort_t* __restrict__ Tlo,
                                       int K, int N, int bx, int by) {
    __shared__ float tile[32][33];
    int n0 = bx * 32, k0 = by * 32;
    int tx = threadIdx.x & 31, ty = threadIdx.x >> 5;
#pragma unroll
    for (int i = 0; i < 4; ++i) {
        int k = ty + i * 8;
        tile[k][tx] = W[(size_t)(k0 + k) * N + n0 + tx];
    }
    __syncthreads();
#pragma unroll
    for (int i = 0; i < 4; ++i) {
        int nn = ty + i * 8;
        float v = tile[tx][nn];
        ushort_t hi, lo; split_bf16(v, hi, lo);
        Thi[(size_t)(n0 + nn) * K + k0 + tx] = hi;
        Tlo[(size_t)(n0 + nn) * K + k0 + tx] = lo;
    }
}

__global__ __launch_bounds__(256) void k_prep(
    const float* __restrict__ W1, const float* __restrict__ W2, const float* __restrict__ mem,
    ushort_t* __restrict__ W1Thi, ushort_t* __restrict__ W1Tlo,
    ushort_t* __restrict__ W2Thi, ushort_t* __restrict__ W2Tlo,
    ushort_t* __restrict__ MThi, ushort_t* __restrict__ MTlo,
    ushort_t* __restrict__ Mhi, ushort_t* __restrict__ Mlo) {
    int b = blockIdx.x;
    if (b < 600)       dsplit(W1, W1Thi, W1Tlo, XDIM, DHID, b % 24, b / 24);
    else if (b < 1176) dsplit(W2, W2Thi, W2Tlo, DHID, DOUT, (b - 600) % 24, (b - 600) / 24);
    else if (b < 1224) dsplit(mem, MThi, MTlo, MEMK, DOUT, (b - 1176) % 24, (b - 1176) / 24);
    else {
        int i = (b - 1224) * 256 + threadIdx.x;
        if (i < MEMK * 768) {
            ushort_t h, l; split_bf16(mem[i], h, l);
            Mhi[i] = h; Mlo[i] = l;
        }
    }
}

// ---------------- CSR build + graph boundaries (fused) ----------------
__global__ void k_fill_bucket(const int* __restrict__ col, int* __restrict__ counts,
                              int* __restrict__ bucket, int E,
                              const int* __restrict__ batch, int* __restrict__ gstart,
                              int* __restrict__ gend, int n) {
    if (blockIdx.x < 1024) {
        for (int e = blockIdx.x * blockDim.x + threadIdx.x; e < E; e += 1024 * blockDim.x) {
            int c = col[e];
            if ((unsigned)c < (unsigned)NNODES) {
                int p = atomicAdd(&counts[c], 1);
                if (p < BUCKET_CAP) bucket[c * BUCKET_CAP + p] = e;
            }
        }
    } else {
        int i = (blockIdx.x - 1024) * 256 + threadIdx.x;
        if (i >= n) return;
        int b = batch[i];
        if ((unsigned)b >= (unsigned)NGRAPH) return;
        if (i == 0 || batch[i - 1] != b) gstart[b] = i;
        if (i == n - 1 || batch[i + 1] != b) gend[b] = i + 1;
    }
}

// ---------------- aggregate edges -> X planes (bf16 hi/lo) ----------------
__global__ __launch_bounds__(192) void k_aggregate(
    const float* __restrict__ feature, const float* __restrict__ edge_attr,
    const float* __restrict__ ppr, const float* __restrict__ Ws, const float* __restrict__ bs,
    const int* __restrict__ bucket, const int* __restrict__ counts,
    ushort_t* __restrict__ Xhi, ushort_t* __restrict__ Xlo) {
    int n = blockIdx.x;
    int t = threadIdx.x;
    const float4* frow = (const float4*)(feature + (size_t)n * DIN);
    float4 acc = frow[t];
    int deg = min(counts[n], BUCKET_CAP);
    const int* bk = bucket + n * BUCKET_CAP;
    for (int j = 0; j < deg; ++j) {
        int e = bk[j];
        float4 v = ((const float4*)(edge_attr + (size_t)e * DIN))[t];
        acc.x += v.x; acc.y += v.y; acc.z += v.z; acc.w += v.w;
    }
    ushort4 h4, l4;
    split_bf16(acc.x, h4.x, l4.x); split_bf16(acc.y, h4.y, l4.y);
    split_bf16(acc.z, h4.z, l4.z); split_bf16(acc.w, h4.w, l4.w);
    *(ushort4*)(Xhi + (size_t)n * XDIM + t * 4) = h4;
    *(ushort4*)(Xlo + (size_t)n * XDIM + t * 4) = l4;
    if (t < DSTRUCT / 4) {
        float p = ppr[n];
        int k = t * 4;
        float4 s;
        s.x = fmaxf(p * Ws[k+0] + bs[k+0], 0.f);
        s.y = fmaxf(p * Ws[k+1] + bs[k+1], 0.f);
        s.z = fmaxf(p * Ws[k+2] + bs[k+2], 0.f);
        s.w = fmaxf(p * Ws[k+3] + bs[k+3], 0.f);
        ushort4 sh, sl;
        split_bf16(s.x, sh.x, sl.x); split_bf16(s.y, sh.y, sl.y);
        split_bf16(s.z, sh.z, sl.z); split_bf16(s.w, sh.w, sl.w);
        *(ushort4*)(Xhi + (size_t)n * XDIM + DIN + k) = sh;
        *(ushort4*)(Xlo + (size_t)n * XDIM + DIN + k) = sl;
    }
}

// ---------------- split-bf16 MFMA GEMM, B streamed from L2 ----------------
// C[M][N] = act(A@B^T + bias);  A planes [M][K], BT planes [N][K] (bf16 hi/lo)
// BM=64 BN=128 BK=32, 256 thr = 4 waves (2M x 2N).  Only A staged in LDS (dbuf,
// R5's consecutive-lane-contiguous staging).  B frags load straight from L2:
// one b128 frag-load = 16 cols x 4 kchunks = 16 full 64B lines, zero over-read.
#define LA_LO  2048
#define LA_BUF 4096

template<int ACT, int OUTMODE>   // ACT: 0 none, 1 prelu ; OUTMODE: 1 planes, 2 f32+planes
__global__ __launch_bounds__(256, 4) void k_gemm_mfma(
    const ushort_t* __restrict__ Ahi, const ushort_t* __restrict__ Alo,
    const ushort_t* __restrict__ Bhi, const ushort_t* __restrict__ Blo,
    const float* __restrict__ bias, const float* __restrict__ act_p,
    float* __restrict__ Cf, ushort_t* __restrict__ Chi, ushort_t* __restrict__ Clo,
    int M, int N, int K) {
    __shared__ ushort_t lds[2 * LA_BUF];    // 16 KB
    int tid = threadIdx.x;
    int l = tid & 63, w = tid >> 6;

    int nbx = N / 128;
    int nwg = nbx * (M / 64);
    int bid = blockIdx.y * nbx + blockIdx.x;
    int q = nwg >> 3;
    int nb = (bid & 7) * q + (bid >> 3);
    int bx = nb % nbx, by = nb / nbx;
    int m0 = by * 64, n0 = bx * 128;

    int wm = w >> 1, wn = w & 1;

    f32x4 acc[2][4];
#pragma unroll
    for (int m = 0; m < 2; ++m)
#pragma unroll
        for (int n = 0; n < 4; ++n) acc[m][n] = (f32x4){0.f, 0.f, 0.f, 0.f};

    // A staging: wave w rows w*16..+15; lane: row w*16 + l/4, 16B chunk l&3
    int srow = w * 16 + (l >> 2);
    int sc   = (l & 3) * 8;
    const ushort_t* agh = Ahi + (size_t)(m0 + srow) * K + sc;
    const ushort_t* agl = Alo + (size_t)(m0 + srow) * K + sc;

    int c0 = l >> 4, li = l & 15;
    // B frag base: lane (c0, li) covers BT row (col) n0 + wn*64 + li, kchunk c0
    const ushort_t* bgh = Bhi + (size_t)(n0 + wn * 64 + li) * K + c0 * 8;
    const ushort_t* bgl = Blo + (size_t)(n0 + wn * 64 + li) * K + c0 * 8;

    gld16(agh, lds + w * 512);
    gld16(agl, lds + LA_LO + w * 512);

    int NT = K / 32;
    for (int kt = 0; kt < NT; ++kt) {
        int cur = kt & 1;
        __syncthreads();
        if (kt + 1 < NT) {
            int ko = (kt + 1) * 32;
            ushort_t* b = lds + (cur ^ 1) * LA_BUF;
            gld16(agh + ko, b + w * 512);
            gld16(agl + ko, b + LA_LO + w * 512);
        }
        const ushort_t* cb = lds + cur * LA_BUF;
        int kb = kt * 32;
        bf16x8 ah[2], al[2], bh[4], bl[4];
#pragma unroll
        for (int n = 0; n < 4; ++n) {
            bh[n] = *(const bf16x8*)(bgh + (size_t)(n * 16) * K + kb);
            bl[n] = *(const bf16x8*)(bgl + (size_t)(n * 16) * K + kb);
        }
#pragma unroll
        for (int m = 0; m < 2; ++m) {
            ah[m] = *(const bf16x8*)(cb + (wm * 32 + m * 16 + li) * 32 + c0 * 8);
            al[m] = *(const bf16x8*)(cb + LA_LO + (wm * 32 + m * 16 + li) * 32 + c0 * 8);
        }
#pragma unroll
        for (int m = 0; m < 2; ++m)
#pragma unroll
            for (int n = 0; n < 4; ++n) {
                acc[m][n] = __builtin_amdgcn_mfma_f32_16x16x32_bf16(ah[m], bh[n], acc[m][n], 0, 0, 0);
                acc[m][n] = __builtin_amdgcn_mfma_f32_16x16x32_bf16(ah[m], bl[n], acc[m][n], 0, 0, 0);
                acc[m][n] = __builtin_amdgcn_mfma_f32_16x16x32_bf16(al[m], bh[n], acc[m][n], 0, 0, 0);
            }
    }

    float ap = (ACT == 1) ? *act_p : 0.f;
#pragma unroll
    for (int m = 0; m < 2; ++m)
#pragma unroll
        for (int n = 0; n < 4; ++n) {
            int col = n0 + wn * 64 + n * 16 + (l & 15);
            float bv = bias[col];
#pragma unroll
            for (int r = 0; r < 4; ++r) {
                int row = m0 + wm * 32 + m * 16 + (l >> 4) * 4 + r;
                float x = acc[m][n][r] + bv;
                if (ACT == 1) x = x > 0.f ? x : ap * x;
                ushort_t hi, lo; split_bf16(x, hi, lo);
                Chi[(size_t)row * N + col] = hi;
                Clo[(size_t)row * N + col] = lo;
                if (OUTMODE == 2) Cf[(size_t)row * N + col] = x;
            }
        }
}

// ---------------- scatter-mean pooling (f32 nf) -> gfeatT [768][64] ----------------
__global__ __launch_bounds__(128) void k_pool(const float* __restrict__ nf,
                                              const int* __restrict__ gstart, const int* __restrict__ gend,
                                              float* __restrict__ gfeatT) {
    int g = blockIdx.x, d = blockIdx.y * 128 + threadIdx.x;
    int s = gstart[g], e = gend[g];
    float a = 0.f;
    for (int n = s; n < e; ++n) a += nf[(size_t)n * DOUT + d];
    gfeatT[(size_t)d * 64 + g] = a / fmaxf((float)(e - s), 1.f);
}

// ---------------- pooled MLP, transpose-fed ----------------
template<int ACT>   // 2: tanh, write OutT[n][m] ; 0: none, write OutR[m][n]
__global__ __launch_bounds__(256) void k_mlp_t(const float* __restrict__ AT, const float* __restrict__ B,
                                               const float* __restrict__ bias,
                                               float* __restrict__ OutT, float* __restrict__ OutR) {
    __shared__ float red[4][64];
    int n = blockIdx.x;
    int l = threadIdx.x & 63, qw = threadIdx.x >> 6;
    float s = 0.f;
    const float* a = AT + l;
    const float* b = B + n;
#pragma unroll 8
    for (int k = qw * 192; k < qw * 192 + 192; ++k)
        s = fmaf(a[k * 64], b[k * 768], s);
    red[qw][l] = s;
    __syncthreads();
    if (threadIdx.x < 64) {
        float v = red[0][l] + red[1][l] + red[2][l] + red[3][l] + bias[n];
        if (ACT == 2) { v = tanhf(v); OutT[n * 64 + l] = v; }
        else OutR[(size_t)l * 768 + n] = v;
    }
}

// ---------------- fused MFMA attention: scores -> softmax -> PV + loss ----------------
__global__ __launch_bounds__(256) void k_attn(
    const ushort_t* __restrict__ NFhi, const ushort_t* __restrict__ NFlo,
    const ushort_t* __restrict__ Mhi,  const ushort_t* __restrict__ Mlo,
    const ushort_t* __restrict__ MThi, const ushort_t* __restrict__ MTlo,
    const float* __restrict__ nf, float* __restrict__ re, float* __restrict__ lossac) {
    __shared__ ushort_t Ah[96 * 32 * 8];
    __shared__ ushort_t Al[96 * 32 * 8];
    __shared__ ushort_t Wp[2][32 * 64];
    __shared__ float xch[4][32];
    __shared__ float lred[4];
    int tid = threadIdx.x, l = tid & 63, w = tid >> 6;
    int g = l >> 4, li = l & 15;
    int base = blockIdx.x * 32;

    for (int i = w * 12; i < w * 12 + 12; ++i) {
        int kc = i * 2 + (l >> 5), row = l & 31;
        gld16(NFhi + (size_t)(base + row) * 768 + kc * 8, Ah + i * 512);
        gld16(NFlo + (size_t)(base + row) * 768 + kc * 8, Al + i * 512);
    }
    __syncthreads();

    f32x4 sacc[2];
    sacc[0] = (f32x4){0.f,0.f,0.f,0.f}; sacc[1] = (f32x4){0.f,0.f,0.f,0.f};
    int slot = w * 16 + li;
#pragma unroll 4
    for (int kt = 0; kt < 24; ++kt) {
        bf16x8 ah0 = *(const bf16x8*)(Ah + (kt * 4 + g) * 256 + li * 8);
        bf16x8 ah1 = *(const bf16x8*)(Ah + (kt * 4 + g) * 256 + (li + 16) * 8);
        bf16x8 al0 = *(const bf16x8*)(Al + (kt * 4 + g) * 256 + li * 8);
        bf16x8 al1 = *(const bf16x8*)(Al + (kt * 4 + g) * 256 + (li + 16) * 8);
        bf16x8 bh  = *(const bf16x8*)(Mhi + (size_t)slot * 768 + kt * 32 + g * 8);
        bf16x8 bl  = *(const bf16x8*)(Mlo + (size_t)slot * 768 + kt * 32 + g * 8);
        sacc[0] = __builtin_amdgcn_mfma_f32_16x16x32_bf16(ah0, bh, sacc[0], 0, 0, 0);
        sacc[0] = __builtin_amdgcn_mfma_f32_16x16x32_bf16(ah0, bl, sacc[0], 0, 0, 0);
        sacc[0] = __builtin_amdgcn_mfma_f32_16x16x32_bf16(al0, bh, sacc[0], 0, 0, 0);
        sacc[1] = __builtin_amdgcn_mfma_f32_16x16x32_bf16(ah1, bh, sacc[1], 0, 0, 0);
        sacc[1] = __builtin_amdgcn_mfma_f32_16x16x32_bf16(ah1, bl, sacc[1], 0, 0, 0);
        sacc[1] = __builtin_amdgcn_mfma_f32_16x16x32_bf16(al1, bh, sacc[1], 0, 0, 0);
    }

    float mxv[8];
#pragma unroll
    for (int m = 0; m < 2; ++m)
#pragma unroll
        for (int r = 0; r < 4; ++r) {
            float v = sacc[m][r];
            v = fmaxf(v, __shfl_xor(v, 1)); v = fmaxf(v, __shfl_xor(v, 2));
            v = fmaxf(v, __shfl_xor(v, 4)); v = fmaxf(v, __shfl_xor(v, 8));
            mxv[m * 4 + r] = v;
        }
    if (li == 0) {
#pragma unroll
        for (int m = 0; m < 2; ++m)
#pragma unroll
            for (int r = 0; r < 4; ++r) xch[w][m * 16 + g * 4 + r] = mxv[m * 4 + r];
    }
    __syncthreads();
    float ev[8], sv[8];
#pragma unroll
    for (int m = 0; m < 2; ++m)
#pragma unroll
        for (int r = 0; r < 4; ++r) {
            int row = m * 16 + g * 4 + r;
            float mx = fmaxf(fmaxf(xch[0][row], xch[1][row]), fmaxf(xch[2][row], xch[3][row]));
            float e = __expf(sacc[m][r] - mx);
            ev[m * 4 + r] = e;
            float s = e;
            s += __shfl_xor(s, 1); s += __shfl_xor(s, 2);
            s += __shfl_xor(s, 4); s += __shfl_xor(s, 8);
            sv[m * 4 + r] = s;
        }
    __syncthreads();
    if (li == 0) {
#pragma unroll
        for (int m = 0; m < 2; ++m)
#pragma unroll
            for (int r = 0; r < 4; ++r) xch[w][m * 16 + g * 4 + r] = sv[m * 4 + r];
    }
    __syncthreads();
#pragma unroll
    for (int m = 0; m < 2; ++m)
#pragma unroll
        for (int r = 0; r < 4; ++r) {
            int row = m * 16 + g * 4 + r;
            float tot = xch[0][row] + xch[1][row] + xch[2][row] + xch[3][row];
            float wv = ev[m * 4 + r] / tot;
            ushort_t hi, lo; split_bf16(wv, hi, lo);
            int idx = row * 64 + (slot ^ ((row & 7) << 3));
            Wp[0][idx] = hi; Wp[1][idx] = lo;
        }
    __syncthreads();

    bf16x8 wah[2][2], wal[2][2];
#pragma unroll
    for (int m = 0; m < 2; ++m)
#pragma unroll
        for (int kt2 = 0; kt2 < 2; ++kt2) {
            int row = m * 16 + li;
            int k8 = kt2 * 4 + g;
            int idx = row * 64 + ((k8 * 8) ^ ((row & 7) << 3));
            wah[m][kt2] = *(const bf16x8*)&Wp[0][idx];
            wal[m][kt2] = *(const bf16x8*)&Wp[1][idx];
        }
    float lp = 0.f;
#pragma unroll 2
    for (int nfi = 0; nfi < 12; ++nfi) {
        int col = w * 192 + nfi * 16 + li;
        f32x4 pacc[2];
        pacc[0] = (f32x4){0.f,0.f,0.f,0.f}; pacc[1] = (f32x4){0.f,0.f,0.f,0.f};
#pragma unroll
        for (int kt2 = 0; kt2 < 2; ++kt2) {
            bf16x8 bh = *(const bf16x8*)(MThi + (size_t)col * 64 + kt2 * 32 + g * 8);
            bf16x8 bl = *(const bf16x8*)(MTlo + (size_t)col * 64 + kt2 * 32 + g * 8);
#pragma unroll
            for (int m = 0; m < 2; ++m) {
                pacc[m] = __builtin_amdgcn_mfma_f32_16x16x32_bf16(wah[m][kt2], bh, pacc[m], 0, 0, 0);
                pacc[m] = __builtin_amdgcn_mfma_f32_16x16x32_bf16(wah[m][kt2], bl, pacc[m], 0, 0, 0);
                pacc[m] = __builtin_amdgcn_mfma_f32_16x16x32_bf16(wal[m][kt2], bh, pacc[m], 0, 0, 0);
            }
        }
#pragma unroll
        for (int m = 0; m < 2; ++m)
#pragma unroll
            for (int r = 0; r < 4; ++r) {
                int row = base + m * 16 + g * 4 + r;
                float v = pacc[m][r] * (1.f / 64.f);
                float x = nf[(size_t)row * 768 + col];
                re[(size_t)row * 768 + col] = v;
                float d = x - v;
                lp = fmaf(d, d, lp);
            }
    }
    for (int o = 32; o; o >>= 1) lp += __shfl_xor(lp, o);
    if (l == 0) lred[w] = lp;
    __syncthreads();
    if (tid == 0) atomicAdd(lossac, lred[0] + lred[1] + lred[2] + lred[3]);
}

__global__ void k_loss_final(const float* __restrict__ acc, float* __restrict__ out, float invn) {
    if (threadIdx.x == 0 && blockIdx.x == 0) out[0] = acc[0] * invn;
}

// ---------------- launch ----------------
extern "C" void kernel_launch(void* const* d_in, const int* in_sizes, int n_in,
                              void* d_out, int out_size, void* d_ws, size_t ws_size,
                              hipStream_t stream) {
    const float* feature  = (const float*)d_in[0];
    const float* ppr      = (const float*)d_in[1];
    const float* edge_attr= (const float*)d_in[2];
    const float* Ws       = (const float*)d_in[3];
    const float* bs       = (const float*)d_in[4];
    const float* W1       = (const float*)d_in[5];
    const float* b1       = (const float*)d_in[6];
    const float* prelu_a  = (const float*)d_in[7];
    const float* W2       = (const float*)d_in[8];
    const float* b2       = (const float*)d_in[9];
    const float* Wp1      = (const float*)d_in[10];
    const float* bp1      = (const float*)d_in[11];
    const float* Wp2      = (const float*)d_in[12];
    const float* bp2      = (const float*)d_in[13];
    const float* memory   = (const float*)d_in[14];
    const int*   edge_index = (const int*)d_in[15];
    const int*   batch_ids  = (const int*)d_in[16];

    const int E = in_sizes[15] / 2;
    const int N = in_sizes[0] / DIN;
    const int* col = edge_index + E;

    char* ws = (char*)d_ws;
    ushort_t* Xhi  = (ushort_t*)(ws + OFF_XHI);
    ushort_t* Xlo  = (ushort_t*)(ws + OFF_XLO);
    ushort_t* Hhi  = (ushort_t*)(ws + OFF_HHI);
    ushort_t* Hlo  = (ushort_t*)(ws + OFF_HLO);
    float*    nf   = (float*)   (ws + OFF_NF);
    ushort_t* NFhi = (ushort_t*)(ws + OFF_NFHI);
    ushort_t* NFlo = (ushort_t*)(ws + OFF_NFLO);
    ushort_t* W1Thi= (ushort_t*)(ws + OFF_W1THI);
    ushort_t* W1Tlo= (ushort_t*)(ws + OFF_W1TLO);
    ushort_t* W2Thi= (ushort_t*)(ws + OFF_W2THI);
    ushort_t* W2Tlo= (ushort_t*)(ws + OFF_W2TLO);
    ushort_t* Mhi  = (ushort_t*)(ws + OFF_MHI);
    ushort_t* Mlo  = (ushort_t*)(ws + OFF_MLO);
    ushort_t* MThi = (ushort_t*)(ws + OFF_MTHI);
    ushort_t* MTlo = (ushort_t*)(ws + OFF_MTLO);
    int*   bucket = (int*)(ws + OFF_BUCKET);
    int*   counts = (int*)(ws + OFF_COUNTS);
    int*   gstart = (int*)(ws + OFF_GSTART);
    int*   gend   = (int*)(ws + OFF_GEND);
    float* lossac = (float*)(ws + OFF_LOSS);
    float* gfeatT = (float*)(ws + OFF_GFEAT);
    float* t1T    = (float*)(ws + OFF_T1);

    float* out_pooled = (float*)d_out;
    float* out_re     = (float*)d_out + NGRAPH * DOUT;
    float* out_loss   = (float*)d_out + NGRAPH * DOUT + (size_t)N * DOUT;

    (void)hipMemsetAsync(ws + ZERO_OFF, 0, ZERO_BYTES, stream);

    k_prep<<<1416, 256, 0, stream>>>(W1, W2, memory, W1Thi, W1Tlo, W2Thi, W2Tlo,
                                     MThi, MTlo, Mhi, Mlo);

    k_fill_bucket<<<1024 + (NNODES + 255) / 256, 256, 0, stream>>>(
        col, counts, bucket, E, batch_ids, gstart, gend, N);
    k_aggregate<<<N, 192, 0, stream>>>(feature, edge_attr, ppr, Ws, bs, bucket, counts, Xhi, Xlo);

    k_gemm_mfma<1, 1><<<dim3(DHID / 128, N / 64), 256, 0, stream>>>(
        Xhi, Xlo, W1Thi, W1Tlo, b1, prelu_a, nullptr, Hhi, Hlo, N, DHID, XDIM);
    k_gemm_mfma<0, 2><<<dim3(DOUT / 128, N / 64), 256, 0, stream>>>(
        Hhi, Hlo, W2Thi, W2Tlo, b2, nullptr, nf, NFhi, NFlo, N, DOUT, DHID);

    k_pool<<<dim3(NGRAPH, 6), 128, 0, stream>>>(nf, gstart, gend, gfeatT);

    k_mlp_t<2><<<768, 256, 0, stream>>>(gfeatT, Wp1, bp1, t1T, nullptr);
    k_mlp_t<0><<<768, 256, 0, stream>>>(t1T, Wp2, bp2, nullptr, out_pooled);

    k_attn<<<N / 32, 256, 0, stream>>>(NFhi, NFlo, Mhi, Mlo, MThi, MTlo, nf, out_re, lossac);
    k_loss_final<<<1, 64, 0, stream>>>(lossac, out_loss, 1.f / (float)((size_t)N * DOUT));
}

// Round 8
// 405.867 us; speedup vs baseline: 1.1525x; 1.1525x over previous
//
#include <hip/hip_runtime.h>
#include <hip/hip_bf16.h>
#include <math.h>

typedef unsigned short ushort_t;
typedef short bf16x8 __attribute__((ext_vector_type(8)));
typedef float f32x4 __attribute__((ext_vector_type(4)));

#define NNODES   8192
#define DIN      768
#define DSTRUCT  32
#define XDIM     800
#define DHID     768
#define DOUT     768
#define MEMK     64
#define NGRAPH   64
#define BUCKET_CAP 128

// ---------------- workspace layout (bytes) ----------------
#define OFF_XHI     0u
#define OFF_XLO     (OFF_XHI  + 8192u*800u*2u)
#define OFF_HHI     (OFF_XLO  + 8192u*800u*2u)
#define OFF_HLO     (OFF_HHI  + 8192u*768u*2u)
#define OFF_NF      (OFF_HLO  + 8192u*768u*2u)     // f32 [8192][768]
#define OFF_NFHI    (OFF_NF   + 8192u*768u*4u)
#define OFF_NFLO    (OFF_NFHI + 8192u*768u*2u)
#define OFF_W1THI   (OFF_NFLO + 8192u*768u*2u)
#define OFF_W1TLO   (OFF_W1THI + 768u*800u*2u)
#define OFF_W2THI   (OFF_W1TLO + 768u*800u*2u)
#define OFF_W2TLO   (OFF_W2THI + 768u*768u*2u)
#define OFF_MHI     (OFF_W2TLO + 768u*768u*2u)
#define OFF_MLO     (OFF_MHI  + 64u*768u*2u)
#define OFF_MTHI    (OFF_MLO  + 64u*768u*2u)
#define OFF_MTLO    (OFF_MTHI + 768u*64u*2u)
#define OFF_BUCKET  (OFF_MTLO + 768u*64u*2u)
#define OFF_COUNTS  (OFF_BUCKET + 8192u*BUCKET_CAP*4u)
#define OFF_GSTART  (OFF_COUNTS + 8192u*4u)
#define OFF_GEND    (OFF_GSTART + 256u)
#define OFF_LOSS    (OFF_GEND + 256u)
#define OFF_GFEAT   (OFF_LOSS + 256u)          // gfeatT [768][64] f32
#define OFF_T1      (OFF_GFEAT + 768u*64u*4u)  // t1T [768][64] f32
#define ZERO_OFF    OFF_COUNTS
#define ZERO_BYTES  (8192u*4u + 256u + 256u + 256u)

// ---------------- helpers ----------------
__device__ __forceinline__ ushort_t bf_rne(float f) {
    unsigned u = __float_as_uint(f);
    return (ushort_t)((u + 0x7FFFu + ((u >> 16) & 1u)) >> 16);
}
__device__ __forceinline__ void split_bf16(float f, ushort_t& hi, ushort_t& lo) {
    ushort_t h = bf_rne(f);
    float fh = __uint_as_float(((unsigned)h) << 16);
    hi = h;
    lo = bf_rne(f - fh);
}
__device__ __forceinline__ void gld16(const void* g, void* l) {
    __builtin_amdgcn_global_load_lds(
        (const __attribute__((address_space(1))) unsigned int*)g,
        (__attribute__((address_space(3))) unsigned int*)l, 16, 0, 0);
}

// ---------------- fused prep: transpose+split W1/W2/mem, split mem ----------------
__device__ __forceinline__ void dsplit(const float* __restrict__ W,
                                       ushort_t* __restrict__ Thi, ushort_t* __restrict__ Tlo,
                                       int K, int N, int bx, int by) {
    __shared__ float tile[32][33];
    int n0 = bx * 32, k0 = by * 32;
    int tx = threadIdx.x & 31, ty = threadIdx.x >> 5;
#pragma unroll
    for (int i = 0; i < 4; ++i) {
        int k = ty + i * 8;
        tile[k][tx] = W[(size_t)(k0 + k) * N + n0 + tx];
    }
    __syncthreads();
#pragma unroll
    for (int i = 0; i < 4; ++i) {
        int nn = ty + i * 8;
        float v = tile[tx][nn];
        ushort_t hi, lo; split_bf16(v, hi, lo);
        Thi[(size_t)(n0 + nn) * K + k0 + tx] = hi;
        Tlo[(size_t)(n0 + nn) * K + k0 + tx] = lo;
    }
}

__global__ __launch_bounds__(256) void k_prep(
    const float* __restrict__ W1, const float* __restrict__ W2, const float* __restrict__ mem,
    ushort_t* __restrict__ W1Thi, ushort_t* __restrict__ W1Tlo,
    ushort_t* __restrict__ W2Thi, ushort_t* __restrict__ W2Tlo,
    ushort_t* __restrict__ MThi, ushort_t* __restrict__ MTlo,
    ushort_t* __restrict__ Mhi, ushort_t* __restrict__ Mlo) {
    int b = blockIdx.x;
    if (b < 600)       dsplit(W1, W1Thi, W1Tlo, XDIM, DHID, b % 24, b / 24);
    else if (b < 1176) dsplit(W2, W2Thi, W2Tlo, DHID, DOUT, (b - 600) % 24, (b - 600) / 24);
    else if (b < 1224) dsplit(mem, MThi, MTlo, MEMK, DOUT, (b - 1176) % 24, (b - 1176) / 24);
    else {
        int i = (b - 1224) * 256 + threadIdx.x;
        if (i < MEMK * 768) {
            ushort_t h, l; split_bf16(mem[i], h, l);
            Mhi[i] = h; Mlo[i] = l;
        }
    }
}

// ---------------- CSR build + graph boundaries (fused) ----------------
__global__ void k_fill_bucket(const int* __restrict__ col, int* __restrict__ counts,
                              int* __restrict__ bucket, int E,
                              const int* __restrict__ batch, int* __restrict__ gstart,
                              int* __restrict__ gend, int n) {
    if (blockIdx.x < 1024) {
        for (int e = blockIdx.x * blockDim.x + threadIdx.x; e < E; e += 1024 * blockDim.x) {
            int c = col[e];
            if ((unsigned)c < (unsigned)NNODES) {
                int p = atomicAdd(&counts[c], 1);
                if (p < BUCKET_CAP) bucket[c * BUCKET_CAP + p] = e;
            }
        }
    } else {
        int i = (blockIdx.x - 1024) * 256 + threadIdx.x;
        if (i >= n) return;
        int b = batch[i];
        if ((unsigned)b >= (unsigned)NGRAPH) return;
        if (i == 0 || batch[i - 1] != b) gstart[b] = i;
        if (i == n - 1 || batch[i + 1] != b) gend[b] = i + 1;
    }
}

// ---------------- aggregate edges -> X planes (bf16 hi/lo) ----------------
__global__ __launch_bounds__(192) void k_aggregate(
    const float* __restrict__ feature, const float* __restrict__ edge_attr,
    const float* __restrict__ ppr, const float* __restrict__ Ws, const float* __restrict__ bs,
    const int* __restrict__ bucket, const int* __restrict__ counts,
    ushort_t* __restrict__ Xhi, ushort_t* __restrict__ Xlo) {
    int n = blockIdx.x;
    int t = threadIdx.x;
    const float4* frow = (const float4*)(feature + (size_t)n * DIN);
    float4 acc = frow[t];
    int deg = min(counts[n], BUCKET_CAP);
    const int* bk = bucket + n * BUCKET_CAP;
    for (int j = 0; j < deg; ++j) {
        int e = bk[j];
        float4 v = ((const float4*)(edge_attr + (size_t)e * DIN))[t];
        acc.x += v.x; acc.y += v.y; acc.z += v.z; acc.w += v.w;
    }
    ushort4 h4, l4;
    split_bf16(acc.x, h4.x, l4.x); split_bf16(acc.y, h4.y, l4.y);
    split_bf16(acc.z, h4.z, l4.z); split_bf16(acc.w, h4.w, l4.w);
    *(ushort4*)(Xhi + (size_t)n * XDIM + t * 4) = h4;
    *(ushort4*)(Xlo + (size_t)n * XDIM + t * 4) = l4;
    if (t < DSTRUCT / 4) {
        float p = ppr[n];
        int k = t * 4;
        float4 s;
        s.x = fmaxf(p * Ws[k+0] + bs[k+0], 0.f);
        s.y = fmaxf(p * Ws[k+1] + bs[k+1], 0.f);
        s.z = fmaxf(p * Ws[k+2] + bs[k+2], 0.f);
        s.w = fmaxf(p * Ws[k+3] + bs[k+3], 0.f);
        ushort4 sh, sl;
        split_bf16(s.x, sh.x, sl.x); split_bf16(s.y, sh.y, sl.y);
        split_bf16(s.z, sh.z, sl.z); split_bf16(s.w, sh.w, sl.w);
        *(ushort4*)(Xhi + (size_t)n * XDIM + DIN + k) = sh;
        *(ushort4*)(Xlo + (size_t)n * XDIM + DIN + k) = sl;
    }
}

// ---------------- split-bf16 MFMA GEMM (R5-proven structure) ----------------
// C[M][N] = act(A@B^T + bias);  A planes [M][K], BT planes [N][K] (bf16 hi/lo)
// BM=64 BN=128 BK=32, 256 thr = 4 waves (2M x 2N), wave tile 32x64.
// LDS per buf (ushort offsets): Ahi[64][32] @0, Alo @2048, Bhi[128][32] @4096, Blo @8192.
// Staging 64B-granular: 4 consecutive lanes cover one row's 32 k-elems contiguously.
#define L_ALO 2048
#define L_BHI 4096
#define L_BLO 8192
#define L_BUF 12288

template<int ACT, int OUTMODE>   // ACT: 0 none, 1 prelu ; OUTMODE: 1 planes, 2 f32+planes
__global__ __launch_bounds__(256) void k_gemm_mfma(
    const ushort_t* __restrict__ Ahi, const ushort_t* __restrict__ Alo,
    const ushort_t* __restrict__ Bhi, const ushort_t* __restrict__ Blo,
    const float* __restrict__ bias, const float* __restrict__ act_p,
    float* __restrict__ Cf, ushort_t* __restrict__ Chi, ushort_t* __restrict__ Clo,
    int M, int N, int K) {
    __shared__ ushort_t lds[2 * L_BUF];
    int tid = threadIdx.x;
    int l = tid & 63, w = tid >> 6;

    int nbx = N / 128;
    int nwg = nbx * (M / 64);
    int bid = blockIdx.y * nbx + blockIdx.x;
    int q = nwg >> 3;
    int nb = (bid & 7) * q + (bid >> 3);
    int bx = nb % nbx, by = nb / nbx;
    int m0 = by * 64, n0 = bx * 128;

    int wm = w >> 1, wn = w & 1;

    f32x4 acc[2][4];
#pragma unroll
    for (int m = 0; m < 2; ++m)
#pragma unroll
        for (int n = 0; n < 4; ++n) acc[m][n] = (f32x4){0.f, 0.f, 0.f, 0.f};

    // staging: lane l covers row (w*16 + l/4), 16B chunk (l&3) of the 64B row
    int srow = w * 16 + (l >> 2);
    int sc   = (l & 3) * 8;
    const ushort_t* agh  = Ahi + (size_t)(m0 + srow) * K + sc;
    const ushort_t* agl  = Alo + (size_t)(m0 + srow) * K + sc;
    const ushort_t* bgh0 = Bhi + (size_t)(n0 + srow) * K + sc;
    const ushort_t* bgh1 = Bhi + (size_t)(n0 + 64 + srow) * K + sc;
    const ushort_t* bgl0 = Blo + (size_t)(n0 + srow) * K + sc;
    const ushort_t* bgl1 = Blo + (size_t)(n0 + 64 + srow) * K + sc;

    int NT = K / 32;

    {
        ushort_t* b = lds;
        gld16(agh,  b + w * 512);
        gld16(agl,  b + L_ALO + w * 512);
        gld16(bgh0, b + L_BHI + w * 512);
        gld16(bgh1, b + L_BHI + 2048 + w * 512);
        gld16(bgl0, b + L_BLO + w * 512);
        gld16(bgl1, b + L_BLO + 2048 + w * 512);
    }

    int c0 = l >> 4;            // kchunk 0..3
    int arow = wm * 32 + (l & 15);
    int bcol = wn * 64 + (l & 15);

    for (int kt = 0; kt < NT; ++kt) {
        int cur = kt & 1;
        __syncthreads();
        if (kt + 1 < NT) {
            int ko = (kt + 1) * 32;
            ushort_t* b = lds + (cur ^ 1) * L_BUF;
            gld16(agh + ko,  b + w * 512);
            gld16(agl + ko,  b + L_ALO + w * 512);
            gld16(bgh0 + ko, b + L_BHI + w * 512);
            gld16(bgh1 + ko, b + L_BHI + 2048 + w * 512);
            gld16(bgl0 + ko, b + L_BLO + w * 512);
            gld16(bgl1 + ko, b + L_BLO + 2048 + w * 512);
        }
        const ushort_t* cb = lds + cur * L_BUF;
        bf16x8 ah[2], al[2], bh[4], bl[4];
#pragma unroll
        for (int m = 0; m < 2; ++m) {
            ah[m] = *(const bf16x8*)(cb + (arow + m * 16) * 32 + c0 * 8);
            al[m] = *(const bf16x8*)(cb + L_ALO + (arow + m * 16) * 32 + c0 * 8);
        }
#pragma unroll
        for (int n = 0; n < 4; ++n) {
            bh[n] = *(const bf16x8*)(cb + L_BHI + (bcol + n * 16) * 32 + c0 * 8);
            bl[n] = *(const bf16x8*)(cb + L_BLO + (bcol + n * 16) * 32 + c0 * 8);
        }
#pragma unroll
        for (int m = 0; m < 2; ++m)
#pragma unroll
            for (int n = 0; n < 4; ++n) {
                acc[m][n] = __builtin_amdgcn_mfma_f32_16x16x32_bf16(ah[m], bh[n], acc[m][n], 0, 0, 0);
                acc[m][n] = __builtin_amdgcn_mfma_f32_16x16x32_bf16(ah[m], bl[n], acc[m][n], 0, 0, 0);
                acc[m][n] = __builtin_amdgcn_mfma_f32_16x16x32_bf16(al[m], bh[n], acc[m][n], 0, 0, 0);
            }
    }

    float ap = (ACT == 1) ? *act_p : 0.f;
#pragma unroll
    for (int m = 0; m < 2; ++m)
#pragma unroll
        for (int n = 0; n < 4; ++n) {
            int col = n0 + wn * 64 + n * 16 + (l & 15);
            float bv = bias[col];
#pragma unroll
            for (int r = 0; r < 4; ++r) {
                int row = m0 + wm * 32 + m * 16 + (l >> 4) * 4 + r;
                float x = acc[m][n][r] + bv;
                if (ACT == 1) x = x > 0.f ? x : ap * x;
                ushort_t hi, lo; split_bf16(x, hi, lo);
                Chi[(size_t)row * N + col] = hi;
                Clo[(size_t)row * N + col] = lo;
                if (OUTMODE == 2) Cf[(size_t)row * N + col] = x;
            }
        }
}

// ---------------- scatter-mean pooling (f32 nf) -> gfeatT [768][64] ----------------
__global__ __launch_bounds__(128) void k_pool(const float* __restrict__ nf,
                                              const int* __restrict__ gstart, const int* __restrict__ gend,
                                              float* __restrict__ gfeatT) {
    int g = blockIdx.x, d = blockIdx.y * 128 + threadIdx.x;
    int s = gstart[g], e = gend[g];
    float a = 0.f;
    for (int n = s; n < e; ++n) a += nf[(size_t)n * DOUT + d];
    gfeatT[(size_t)d * 64 + g] = a / fmaxf((float)(e - s), 1.f);
}

// ---------------- pooled MLP, transpose-fed ----------------
template<int ACT>   // 2: tanh, write OutT[n][m] ; 0: none, write OutR[m][n]
__global__ __launch_bounds__(256) void k_mlp_t(const float* __restrict__ AT, const float* __restrict__ B,
                                               const float* __restrict__ bias,
                                               float* __restrict__ OutT, float* __restrict__ OutR) {
    __shared__ float red[4][64];
    int n = blockIdx.x;
    int l = threadIdx.x & 63, qw = threadIdx.x >> 6;
    float s = 0.f;
    const float* a = AT + l;
    const float* b = B + n;
#pragma unroll 8
    for (int k = qw * 192; k < qw * 192 + 192; ++k)
        s = fmaf(a[k * 64], b[k * 768], s);
    red[qw][l] = s;
    __syncthreads();
    if (threadIdx.x < 64) {
        float v = red[0][l] + red[1][l] + red[2][l] + red[3][l] + bias[n];
        if (ACT == 2) { v = tanhf(v); OutT[n * 64 + l] = v; }
        else OutR[(size_t)l * 768 + n] = v;
    }
}

// ---------------- fused MFMA attention: scores -> softmax -> PV + loss ----------------
__global__ __launch_bounds__(256) void k_attn(
    const ushort_t* __restrict__ NFhi, const ushort_t* __restrict__ NFlo,
    const ushort_t* __restrict__ Mhi,  const ushort_t* __restrict__ Mlo,
    const ushort_t* __restrict__ MThi, const ushort_t* __restrict__ MTlo,
    const float* __restrict__ nf, float* __restrict__ re, float* __restrict__ lossac) {
    __shared__ ushort_t Ah[96 * 32 * 8];
    __shared__ ushort_t Al[96 * 32 * 8];
    __shared__ ushort_t Wp[2][32 * 64];
    __shared__ float xch[4][32];
    __shared__ float lred[4];
    int tid = threadIdx.x, l = tid & 63, w = tid >> 6;
    int g = l >> 4, li = l & 15;
    int base = blockIdx.x * 32;

    for (int i = w * 12; i < w * 12 + 12; ++i) {
        int kc = i * 2 + (l >> 5), row = l & 31;
        gld16(NFhi + (size_t)(base + row) * 768 + kc * 8, Ah + i * 512);
        gld16(NFlo + (size_t)(base + row) * 768 + kc * 8, Al + i * 512);
    }
    __syncthreads();

    f32x4 sacc[2];
    sacc[0] = (f32x4){0.f,0.f,0.f,0.f}; sacc[1] = (f32x4){0.f,0.f,0.f,0.f};
    int slot = w * 16 + li;
#pragma unroll 4
    for (int kt = 0; kt < 24; ++kt) {
        bf16x8 ah0 = *(const bf16x8*)(Ah + (kt * 4 + g) * 256 + li * 8);
        bf16x8 ah1 = *(const bf16x8*)(Ah + (kt * 4 + g) * 256 + (li + 16) * 8);
        bf16x8 al0 = *(const bf16x8*)(Al + (kt * 4 + g) * 256 + li * 8);
        bf16x8 al1 = *(const bf16x8*)(Al + (kt * 4 + g) * 256 + (li + 16) * 8);
        bf16x8 bh  = *(const bf16x8*)(Mhi + (size_t)slot * 768 + kt * 32 + g * 8);
        bf16x8 bl  = *(const bf16x8*)(Mlo + (size_t)slot * 768 + kt * 32 + g * 8);
        sacc[0] = __builtin_amdgcn_mfma_f32_16x16x32_bf16(ah0, bh, sacc[0], 0, 0, 0);
        sacc[0] = __builtin_amdgcn_mfma_f32_16x16x32_bf16(ah0, bl, sacc[0], 0, 0, 0);
        sacc[0] = __builtin_amdgcn_mfma_f32_16x16x32_bf16(al0, bh, sacc[0], 0, 0, 0);
        sacc[1] = __builtin_amdgcn_mfma_f32_16x16x32_bf16(ah1, bh, sacc[1], 0, 0, 0);
        sacc[1] = __builtin_amdgcn_mfma_f32_16x16x32_bf16(ah1, bl, sacc[1], 0, 0, 0);
        sacc[1] = __builtin_amdgcn_mfma_f32_16x16x32_bf16(al1, bh, sacc[1], 0, 0, 0);
    }

    float mxv[8];
#pragma unroll
    for (int m = 0; m < 2; ++m)
#pragma unroll
        for (int r = 0; r < 4; ++r) {
            float v = sacc[m][r];
            v = fmaxf(v, __shfl_xor(v, 1)); v = fmaxf(v, __shfl_xor(v, 2));
            v = fmaxf(v, __shfl_xor(v, 4)); v = fmaxf(v, __shfl_xor(v, 8));
            mxv[m * 4 + r] = v;
        }
    if (li == 0) {
#pragma unroll
        for (int m = 0; m < 2; ++m)
#pragma unroll
            for (int r = 0; r < 4; ++r) xch[w][m * 16 + g * 4 + r] = mxv[m * 4 + r];
    }
    __syncthreads();
    float ev[8], sv[8];
#pragma unroll
    for (int m = 0; m < 2; ++m)
#pragma unroll
        for (int r = 0; r < 4; ++r) {
            int row = m * 16 + g * 4 + r;
            float mx = fmaxf(fmaxf(xch[0][row], xch[1][row]), fmaxf(xch[2][row], xch[3][row]));
            float e = __expf(sacc[m][r] - mx);
            ev[m * 4 + r] = e;
            float s = e;
            s += __shfl_xor(s, 1); s += __shfl_xor(s, 2);
            s += __shfl_xor(s, 4); s += __shfl_xor(s, 8);
            sv[m * 4 + r] = s;
        }
    __syncthreads();
    if (li == 0) {
#pragma unroll
        for (int m = 0; m < 2; ++m)
#pragma unroll
            for (int r = 0; r < 4; ++r) xch[w][m * 16 + g * 4 + r] = sv[m * 4 + r];
    }
    __syncthreads();
#pragma unroll
    for (int m = 0; m < 2; ++m)
#pragma unroll
        for (int r = 0; r < 4; ++r) {
            int row = m * 16 + g * 4 + r;
            float tot = xch[0][row] + xch[1][row] + xch[2][row] + xch[3][row];
            float wv = ev[m * 4 + r] / tot;
            ushort_t hi, lo; split_bf16(wv, hi, lo);
            int idx = row * 64 + (slot ^ ((row & 7) << 3));
            Wp[0][idx] = hi; Wp[1][idx] = lo;
        }
    __syncthreads();

    bf16x8 wah[2][2], wal[2][2];
#pragma unroll
    for (int m = 0; m < 2; ++m)
#pragma unroll
        for (int kt2 = 0; kt2 < 2; ++kt2) {
            int row = m * 16 + li;
            int k8 = kt2 * 4 + g;
            int idx = row * 64 + ((k8 * 8) ^ ((row & 7) << 3));
            wah[m][kt2] = *(const bf16x8*)&Wp[0][idx];
            wal[m][kt2] = *(const bf16x8*)&Wp[1][idx];
        }
    float lp = 0.f;
#pragma unroll 2
    for (int nfi = 0; nfi < 12; ++nfi) {
        int col = w * 192 + nfi * 16 + li;
        f32x4 pacc[2];
        pacc[0] = (f32x4){0.f,0.f,0.f,0.f}; pacc[1] = (f32x4){0.f,0.f,0.f,0.f};
#pragma unroll
        for (int kt2 = 0; kt2 < 2; ++kt2) {
            bf16x8 bh = *(const bf16x8*)(MThi + (size_t)col * 64 + kt2 * 32 + g * 8);
            bf16x8 bl = *(const bf16x8*)(MTlo + (size_t)col * 64 + kt2 * 32 + g * 8);
#pragma unroll
            for (int m = 0; m < 2; ++m) {
                pacc[m] = __builtin_amdgcn_mfma_f32_16x16x32_bf16(wah[m][kt2], bh, pacc[m], 0, 0, 0);
                pacc[m] = __builtin_amdgcn_mfma_f32_16x16x32_bf16(wah[m][kt2], bl, pacc[m], 0, 0, 0);
                pacc[m] = __builtin_amdgcn_mfma_f32_16x16x32_bf16(wal[m][kt2], bh, pacc[m], 0, 0, 0);
            }
        }
#pragma unroll
        for (int m = 0; m < 2; ++m)
#pragma unroll
            for (int r = 0; r < 4; ++r) {
                int row = base + m * 16 + g * 4 + r;
                float v = pacc[m][r] * (1.f / 64.f);
                float x = nf[(size_t)row * 768 + col];
                re[(size_t)row * 768 + col] = v;
                float d = x - v;
                lp = fmaf(d, d, lp);
            }
    }
    for (int o = 32; o; o >>= 1) lp += __shfl_xor(lp, o);
    if (l == 0) lred[w] = lp;
    __syncthreads();
    if (tid == 0) atomicAdd(lossac, lred[0] + lred[1] + lred[2] + lred[3]);
}

__global__ void k_loss_final(const float* __restrict__ acc, float* __restrict__ out, float invn) {
    if (threadIdx.x == 0 && blockIdx.x == 0) out[0] = acc[0] * invn;
}

// ---------------- launch ----------------
extern "C" void kernel_launch(void* const* d_in, const int* in_sizes, int n_in,
                              void* d_out, int out_size, void* d_ws, size_t ws_size,
                              hipStream_t stream) {
    const float* feature  = (const float*)d_in[0];
    const float* ppr      = (const float*)d_in[1];
    const float* edge_attr= (const float*)d_in[2];
    const float* Ws       = (const float*)d_in[3];
    const float* bs       = (const float*)d_in[4];
    const float* W1       = (const float*)d_in[5];
    const float* b1       = (const float*)d_in[6];
    const float* prelu_a  = (const float*)d_in[7];
    const float* W2       = (const float*)d_in[8];
    const float* b2       = (const float*)d_in[9];
    const float* Wp1      = (const float*)d_in[10];
    const float* bp1      = (const float*)d_in[11];
    const float* Wp2      = (const float*)d_in[12];
    const float* bp2      = (const float*)d_in[13];
    const float* memory   = (const float*)d_in[14];
    const int*   edge_index = (const int*)d_in[15];
    const int*   batch_ids  = (const int*)d_in[16];

    const int E = in_sizes[15] / 2;
    const int N = in_sizes[0] / DIN;
    const int* col = edge_index + E;

    char* ws = (char*)d_ws;
    ushort_t* Xhi  = (ushort_t*)(ws + OFF_XHI);
    ushort_t* Xlo  = (ushort_t*)(ws + OFF_XLO);
    ushort_t* Hhi  = (ushort_t*)(ws + OFF_HHI);
    ushort_t* Hlo  = (ushort_t*)(ws + OFF_HLO);
    float*    nf   = (float*)   (ws + OFF_NF);
    ushort_t* NFhi = (ushort_t*)(ws + OFF_NFHI);
    ushort_t* NFlo = (ushort_t*)(ws + OFF_NFLO);
    ushort_t* W1Thi= (ushort_t*)(ws + OFF_W1THI);
    ushort_t* W1Tlo= (ushort_t*)(ws + OFF_W1TLO);
    ushort_t* W2Thi= (ushort_t*)(ws + OFF_W2THI);
    ushort_t* W2Tlo= (ushort_t*)(ws + OFF_W2TLO);
    ushort_t* Mhi  = (ushort_t*)(ws + OFF_MHI);
    ushort_t* Mlo  = (ushort_t*)(ws + OFF_MLO);
    ushort_t* MThi = (ushort_t*)(ws + OFF_MTHI);
    ushort_t* MTlo = (ushort_t*)(ws + OFF_MTLO);
    int*   bucket = (int*)(ws + OFF_BUCKET);
    int*   counts = (int*)(ws + OFF_COUNTS);
    int*   gstart = (int*)(ws + OFF_GSTART);
    int*   gend   = (int*)(ws + OFF_GEND);
    float* lossac = (float*)(ws + OFF_LOSS);
    float* gfeatT = (float*)(ws + OFF_GFEAT);
    float* t1T    = (float*)(ws + OFF_T1);

    float* out_pooled = (float*)d_out;
    float* out_re     = (float*)d_out + NGRAPH * DOUT;
    float* out_loss   = (float*)d_out + NGRAPH * DOUT + (size_t)N * DOUT;

    (void)hipMemsetAsync(ws + ZERO_OFF, 0, ZERO_BYTES, stream);

    k_prep<<<1416, 256, 0, stream>>>(W1, W2, memory, W1Thi, W1Tlo, W2Thi, W2Tlo,
                                     MThi, MTlo, Mhi, Mlo);

    k_fill_bucket<<<1024 + (NNODES + 255) / 256, 256, 0, stream>>>(
        col, counts, bucket, E, batch_ids, gstart, gend, N);
    k_aggregate<<<N, 192, 0, stream>>>(feature, edge_attr, ppr, Ws, bs, bucket, counts, Xhi, Xlo);

    k_gemm_mfma<1, 1><<<dim3(DHID / 128, N / 64), 256, 0, stream>>>(
        Xhi, Xlo, W1Thi, W1Tlo, b1, prelu_a, nullptr, Hhi, Hlo, N, DHID, XDIM);
    k_gemm_mfma<0, 2><<<dim3(DOUT / 128, N / 64), 256, 0, stream>>>(
        Hhi, Hlo, W2Thi, W2Tlo, b2, nullptr, nf, NFhi, NFlo, N, DOUT, DHID);

    k_pool<<<dim3(NGRAPH, 6), 128, 0, stream>>>(nf, gstart, gend, gfeatT);

    k_mlp_t<2><<<768, 256, 0, stream>>>(gfeatT, Wp1, bp1, t1T, nullptr);
    k_mlp_t<0><<<768, 256, 0, stream>>>(t1T, Wp2, bp2, nullptr, out_pooled);

    k_attn<<<N / 32, 256, 0, stream>>>(NFhi, NFlo, Mhi, Mlo, MThi, MTlo, nf, out_re, lossac);
    k_loss_final<<<1, 64, 0, stream>>>(lossac, out_loss, 1.f / (float)((size_t)N * DOUT));
}

// Round 9
// 379.990 us; speedup vs baseline: 1.2310x; 1.0681x over previous
//
#include <hip/hip_runtime.h>
#include <hip/hip_bf16.h>
#include <math.h>

typedef unsigned short ushort_t;
typedef short bf16x8 __attribute__((ext_vector_type(8)));
typedef float f32x4 __attribute__((ext_vector_type(4)));

#define NNODES   8192
#define DIN      768
#define DSTRUCT  32
#define XDIM     800
#define DHID     768
#define DOUT     768
#define MEMK     64
#define NGRAPH   64
#define BUCKET_CAP 128

// ---------------- workspace layout (bytes) ----------------
#define OFF_XHI     0u
#define OFF_XLO     (OFF_XHI  + 8192u*800u*2u)
#define OFF_HHI     (OFF_XLO  + 8192u*800u*2u)
#define OFF_HLO     (OFF_HHI  + 8192u*768u*2u)
#define OFF_NF      (OFF_HLO  + 8192u*768u*2u)     // f32 [8192][768]
#define OFF_NFHI    (OFF_NF   + 8192u*768u*4u)
#define OFF_NFLO    (OFF_NFHI + 8192u*768u*2u)
#define OFF_W1THI   (OFF_NFLO + 8192u*768u*2u)
#define OFF_W1TLO   (OFF_W1THI + 768u*800u*2u)
#define OFF_W2THI   (OFF_W1TLO + 768u*800u*2u)
#define OFF_W2TLO   (OFF_W2THI + 768u*768u*2u)
#define OFF_MHI     (OFF_W2TLO + 768u*768u*2u)
#define OFF_MLO     (OFF_MHI  + 64u*768u*2u)
#define OFF_MTHI    (OFF_MLO  + 64u*768u*2u)
#define OFF_MTLO    (OFF_MTHI + 768u*64u*2u)
#define OFF_BUCKET  (OFF_MTLO + 768u*64u*2u)
#define OFF_COUNTS  (OFF_BUCKET + 8192u*BUCKET_CAP*4u)
#define OFF_GSTART  (OFF_COUNTS + 8192u*4u)
#define OFF_GEND    (OFF_GSTART + 256u)
#define OFF_LOSS    (OFF_GEND + 256u)
#define OFF_GFEAT   (OFF_LOSS + 256u)          // gfeatT [768][64] f32
#define OFF_T1      (OFF_GFEAT + 768u*64u*4u)  // t1T [768][64] f32
#define ZERO_OFF    OFF_COUNTS
#define ZERO_BYTES  (8192u*4u + 256u + 256u + 256u)

// ---------------- helpers ----------------
__device__ __forceinline__ ushort_t bf_rne(float f) {
    unsigned u = __float_as_uint(f);
    return (ushort_t)((u + 0x7FFFu + ((u >> 16) & 1u)) >> 16);
}
__device__ __forceinline__ void split_bf16(float f, ushort_t& hi, ushort_t& lo) {
    ushort_t h = bf_rne(f);
    float fh = __uint_as_float(((unsigned)h) << 16);
    hi = h;
    lo = bf_rne(f - fh);
}
__device__ __forceinline__ void gld16(const void* g, void* l) {
    __builtin_amdgcn_global_load_lds(
        (const __attribute__((address_space(1))) unsigned int*)g,
        (__attribute__((address_space(3))) unsigned int*)l, 16, 0, 0);
}

// ---------------- fused prep: transpose+split W1/W2/mem, split mem ----------------
template<bool WLO>
__device__ __forceinline__ void dsplit(const float* __restrict__ W,
                                       ushort_t* __restrict__ Thi, ushort_t* __restrict__ Tlo,
                                       int K, int N, int bx, int by) {
    __shared__ float tile[32][33];
    int n0 = bx * 32, k0 = by * 32;
    int tx = threadIdx.x & 31, ty = threadIdx.x >> 5;
#pragma unroll
    for (int i = 0; i < 4; ++i) {
        int k = ty + i * 8;
        tile[k][tx] = W[(size_t)(k0 + k) * N + n0 + tx];
    }
    __syncthreads();
#pragma unroll
    for (int i = 0; i < 4; ++i) {
        int nn = ty + i * 8;
        float v = tile[tx][nn];
        ushort_t hi, lo; split_bf16(v, hi, lo);
        Thi[(size_t)(n0 + nn) * K + k0 + tx] = hi;
        if (WLO) Tlo[(size_t)(n0 + nn) * K + k0 + tx] = lo;
    }
}

__global__ __launch_bounds__(256) void k_prep(
    const float* __restrict__ W1, const float* __restrict__ W2, const float* __restrict__ mem,
    ushort_t* __restrict__ W1Thi, ushort_t* __restrict__ W2Thi,
    ushort_t* __restrict__ MThi, ushort_t* __restrict__ MTlo,
    ushort_t* __restrict__ Mhi, ushort_t* __restrict__ Mlo) {
    int b = blockIdx.x;
    if (b < 600)       dsplit<false>(W1, W1Thi, nullptr, XDIM, DHID, b % 24, b / 24);
    else if (b < 1176) dsplit<false>(W2, W2Thi, nullptr, DHID, DOUT, (b - 600) % 24, (b - 600) / 24);
    else if (b < 1224) dsplit<true>(mem, MThi, MTlo, MEMK, DOUT, (b - 1176) % 24, (b - 1176) / 24);
    else {
        int i = (b - 1224) * 256 + threadIdx.x;
        if (i < MEMK * 768) {
            ushort_t h, l; split_bf16(mem[i], h, l);
            Mhi[i] = h; Mlo[i] = l;
        }
    }
}

// ---------------- CSR build + graph boundaries (fused) ----------------
__global__ void k_fill_bucket(const int* __restrict__ col, int* __restrict__ counts,
                              int* __restrict__ bucket, int E,
                              const int* __restrict__ batch, int* __restrict__ gstart,
                              int* __restrict__ gend, int n) {
    if (blockIdx.x < 1024) {
        for (int e = blockIdx.x * blockDim.x + threadIdx.x; e < E; e += 1024 * blockDim.x) {
            int c = col[e];
            if ((unsigned)c < (unsigned)NNODES) {
                int p = atomicAdd(&counts[c], 1);
                if (p < BUCKET_CAP) bucket[c * BUCKET_CAP + p] = e;
            }
        }
    } else {
        int i = (blockIdx.x - 1024) * 256 + threadIdx.x;
        if (i >= n) return;
        int b = batch[i];
        if ((unsigned)b >= (unsigned)NGRAPH) return;
        if (i == 0 || batch[i - 1] != b) gstart[b] = i;
        if (i == n - 1 || batch[i + 1] != b) gend[b] = i + 1;
    }
}

// ---------------- aggregate edges -> X planes (bf16 hi/lo) ----------------
__global__ __launch_bounds__(192) void k_aggregate(
    const float* __restrict__ feature, const float* __restrict__ edge_attr,
    const float* __restrict__ ppr, const float* __restrict__ Ws, const float* __restrict__ bs,
    const int* __restrict__ bucket, const int* __restrict__ counts,
    ushort_t* __restrict__ Xhi, ushort_t* __restrict__ Xlo) {
    int n = blockIdx.x;
    int t = threadIdx.x;
    const float4* frow = (const float4*)(feature + (size_t)n * DIN);
    float4 acc = frow[t];
    int deg = min(counts[n], BUCKET_CAP);
    const int* bk = bucket + n * BUCKET_CAP;
    for (int j = 0; j < deg; ++j) {
        int e = bk[j];
        float4 v = ((const float4*)(edge_attr + (size_t)e * DIN))[t];
        acc.x += v.x; acc.y += v.y; acc.z += v.z; acc.w += v.w;
    }
    ushort4 h4, l4;
    split_bf16(acc.x, h4.x, l4.x); split_bf16(acc.y, h4.y, l4.y);
    split_bf16(acc.z, h4.z, l4.z); split_bf16(acc.w, h4.w, l4.w);
    *(ushort4*)(Xhi + (size_t)n * XDIM + t * 4) = h4;
    *(ushort4*)(Xlo + (size_t)n * XDIM + t * 4) = l4;
    if (t < DSTRUCT / 4) {
        float p = ppr[n];
        int k = t * 4;
        float4 s;
        s.x = fmaxf(p * Ws[k+0] + bs[k+0], 0.f);
        s.y = fmaxf(p * Ws[k+1] + bs[k+1], 0.f);
        s.z = fmaxf(p * Ws[k+2] + bs[k+2], 0.f);
        s.w = fmaxf(p * Ws[k+3] + bs[k+3], 0.f);
        ushort4 sh, sl;
        split_bf16(s.x, sh.x, sl.x); split_bf16(s.y, sh.y, sl.y);
        split_bf16(s.z, sh.z, sl.z); split_bf16(s.w, sh.w, sl.w);
        *(ushort4*)(Xhi + (size_t)n * XDIM + DIN + k) = sh;
        *(ushort4*)(Xlo + (size_t)n * XDIM + DIN + k) = sl;
    }
}

// ---------------- split-bf16 MFMA GEMM, bf16 weights (2-pass) ----------------
// C[M][N] = act((Ahi+Alo) @ bf16(B)^T + bias);  A planes [M][K], BT hi plane [N][K]
// BM=64 BN=128 BK=32, 256 thr = 4 waves (2M x 2N), wave tile 32x64.
// LDS per buf (ushort offsets): Ahi[64][32] @0, Alo @2048, Bhi[128][32] @4096.
// Staging 64B-granular: 4 consecutive lanes cover one row's 32 k-elems contiguously.
#define L_ALO 2048
#define L_BHI 4096
#define L_BUF 8192

template<int ACT, int OUTMODE>   // ACT: 0 none, 1 prelu ; OUTMODE: 1 planes, 2 f32+planes
__global__ __launch_bounds__(256) void k_gemm_mfma(
    const ushort_t* __restrict__ Ahi, const ushort_t* __restrict__ Alo,
    const ushort_t* __restrict__ Bhi,
    const float* __restrict__ bias, const float* __restrict__ act_p,
    float* __restrict__ Cf, ushort_t* __restrict__ Chi, ushort_t* __restrict__ Clo,
    int M, int N, int K) {
    __shared__ ushort_t lds[2 * L_BUF];
    int tid = threadIdx.x;
    int l = tid & 63, w = tid >> 6;

    int nbx = N / 128;
    int nwg = nbx * (M / 64);
    int bid = blockIdx.y * nbx + blockIdx.x;
    int q = nwg >> 3;
    int nb = (bid & 7) * q + (bid >> 3);
    int bx = nb % nbx, by = nb / nbx;
    int m0 = by * 64, n0 = bx * 128;

    int wm = w >> 1, wn = w & 1;

    f32x4 acc[2][4];
#pragma unroll
    for (int m = 0; m < 2; ++m)
#pragma unroll
        for (int n = 0; n < 4; ++n) acc[m][n] = (f32x4){0.f, 0.f, 0.f, 0.f};

    // staging: lane l covers row (w*16 + l/4), 16B chunk (l&3) of the 64B row
    int srow = w * 16 + (l >> 2);
    int sc   = (l & 3) * 8;
    const ushort_t* agh  = Ahi + (size_t)(m0 + srow) * K + sc;
    const ushort_t* agl  = Alo + (size_t)(m0 + srow) * K + sc;
    const ushort_t* bgh0 = Bhi + (size_t)(n0 + srow) * K + sc;
    const ushort_t* bgh1 = Bhi + (size_t)(n0 + 64 + srow) * K + sc;

    int NT = K / 32;

    {
        ushort_t* b = lds;
        gld16(agh,  b + w * 512);
        gld16(agl,  b + L_ALO + w * 512);
        gld16(bgh0, b + L_BHI + w * 512);
        gld16(bgh1, b + L_BHI + 2048 + w * 512);
    }

    int c0 = l >> 4;            // kchunk 0..3
    int arow = wm * 32 + (l & 15);
    int bcol = wn * 64 + (l & 15);

    for (int kt = 0; kt < NT; ++kt) {
        int cur = kt & 1;
        __syncthreads();
        if (kt + 1 < NT) {
            int ko = (kt + 1) * 32;
            ushort_t* b = lds + (cur ^ 1) * L_BUF;
            gld16(agh + ko,  b + w * 512);
            gld16(agl + ko,  b + L_ALO + w * 512);
            gld16(bgh0 + ko, b + L_BHI + w * 512);
            gld16(bgh1 + ko, b + L_BHI + 2048 + w * 512);
        }
        const ushort_t* cb = lds + cur * L_BUF;
        bf16x8 ah[2], al[2], bh[4];
#pragma unroll
        for (int m = 0; m < 2; ++m) {
            ah[m] = *(const bf16x8*)(cb + (arow + m * 16) * 32 + c0 * 8);
            al[m] = *(const bf16x8*)(cb + L_ALO + (arow + m * 16) * 32 + c0 * 8);
        }
#pragma unroll
        for (int n = 0; n < 4; ++n)
            bh[n] = *(const bf16x8*)(cb + L_BHI + (bcol + n * 16) * 32 + c0 * 8);
#pragma unroll
        for (int m = 0; m < 2; ++m)
#pragma unroll
            for (int n = 0; n < 4; ++n) {
                acc[m][n] = __builtin_amdgcn_mfma_f32_16x16x32_bf16(ah[m], bh[n], acc[m][n], 0, 0, 0);
                acc[m][n] = __builtin_amdgcn_mfma_f32_16x16x32_bf16(al[m], bh[n], acc[m][n], 0, 0, 0);
            }
    }

    float ap = (ACT == 1) ? *act_p : 0.f;
#pragma unroll
    for (int m = 0; m < 2; ++m)
#pragma unroll
        for (int n = 0; n < 4; ++n) {
            int col = n0 + wn * 64 + n * 16 + (l & 15);
            float bv = bias[col];
#pragma unroll
            for (int r = 0; r < 4; ++r) {
                int row = m0 + wm * 32 + m * 16 + (l >> 4) * 4 + r;
                float x = acc[m][n][r] + bv;
                if (ACT == 1) x = x > 0.f ? x : ap * x;
                ushort_t hi, lo; split_bf16(x, hi, lo);
                Chi[(size_t)row * N + col] = hi;
                Clo[(size_t)row * N + col] = lo;
                if (OUTMODE == 2) Cf[(size_t)row * N + col] = x;
            }
        }
}

// ---------------- scatter-mean pooling (f32 nf) -> gfeatT [768][64] ----------------
__global__ __launch_bounds__(128) void k_pool(const float* __restrict__ nf,
                                              const int* __restrict__ gstart, const int* __restrict__ gend,
                                              float* __restrict__ gfeatT) {
    int g = blockIdx.x, d = blockIdx.y * 128 + threadIdx.x;
    int s = gstart[g], e = gend[g];
    float a = 0.f;
    for (int n = s; n < e; ++n) a += nf[(size_t)n * DOUT + d];
    gfeatT[(size_t)d * 64 + g] = a / fmaxf((float)(e - s), 1.f);
}

// ---------------- pooled MLP, transpose-fed ----------------
template<int ACT>   // 2: tanh, write OutT[n][m] ; 0: none, write OutR[m][n]
__global__ __launch_bounds__(256) void k_mlp_t(const float* __restrict__ AT, const float* __restrict__ B,
                                               const float* __restrict__ bias,
                                               float* __restrict__ OutT, float* __restrict__ OutR) {
    __shared__ float red[4][64];
    int n = blockIdx.x;
    int l = threadIdx.x & 63, qw = threadIdx.x >> 6;
    float s = 0.f;
    const float* a = AT + l;
    const float* b = B + n;
#pragma unroll 8
    for (int k = qw * 192; k < qw * 192 + 192; ++k)
        s = fmaf(a[k * 64], b[k * 768], s);
    red[qw][l] = s;
    __syncthreads();
    if (threadIdx.x < 64) {
        float v = red[0][l] + red[1][l] + red[2][l] + red[3][l] + bias[n];
        if (ACT == 2) { v = tanhf(v); OutT[n * 64 + l] = v; }
        else OutR[(size_t)l * 768 + n] = v;
    }
}

// ---------------- fused MFMA attention: scores -> softmax -> PV + loss ----------------
__global__ __launch_bounds__(256) void k_attn(
    const ushort_t* __restrict__ NFhi, const ushort_t* __restrict__ NFlo,
    const ushort_t* __restrict__ Mhi,  const ushort_t* __restrict__ Mlo,
    const ushort_t* __restrict__ MThi, const ushort_t* __restrict__ MTlo,
    const float* __restrict__ nf, float* __restrict__ re, float* __restrict__ lossac) {
    __shared__ ushort_t Ah[96 * 32 * 8];
    __shared__ ushort_t Al[96 * 32 * 8];
    __shared__ ushort_t Wp[2][32 * 64];
    __shared__ float xch[4][32];
    __shared__ float lred[4];
    int tid = threadIdx.x, l = tid & 63, w = tid >> 6;
    int g = l >> 4, li = l & 15;
    int base = blockIdx.x * 32;

    for (int i = w * 12; i < w * 12 + 12; ++i) {
        int kc = i * 2 + (l >> 5), row = l & 31;
        gld16(NFhi + (size_t)(base + row) * 768 + kc * 8, Ah + i * 512);
        gld16(NFlo + (size_t)(base + row) * 768 + kc * 8, Al + i * 512);
    }
    __syncthreads();

    f32x4 sacc[2];
    sacc[0] = (f32x4){0.f,0.f,0.f,0.f}; sacc[1] = (f32x4){0.f,0.f,0.f,0.f};
    int slot = w * 16 + li;
#pragma unroll 4
    for (int kt = 0; kt < 24; ++kt) {
        bf16x8 ah0 = *(const bf16x8*)(Ah + (kt * 4 + g) * 256 + li * 8);
        bf16x8 ah1 = *(const bf16x8*)(Ah + (kt * 4 + g) * 256 + (li + 16) * 8);
        bf16x8 al0 = *(const bf16x8*)(Al + (kt * 4 + g) * 256 + li * 8);
        bf16x8 al1 = *(const bf16x8*)(Al + (kt * 4 + g) * 256 + (li + 16) * 8);
        bf16x8 bh  = *(const bf16x8*)(Mhi + (size_t)slot * 768 + kt * 32 + g * 8);
        bf16x8 bl  = *(const bf16x8*)(Mlo + (size_t)slot * 768 + kt * 32 + g * 8);
        sacc[0] = __builtin_amdgcn_mfma_f32_16x16x32_bf16(ah0, bh, sacc[0], 0, 0, 0);
        sacc[0] = __builtin_amdgcn_mfma_f32_16x16x32_bf16(ah0, bl, sacc[0], 0, 0, 0);
        sacc[0] = __builtin_amdgcn_mfma_f32_16x16x32_bf16(al0, bh, sacc[0], 0, 0, 0);
        sacc[1] = __builtin_amdgcn_mfma_f32_16x16x32_bf16(ah1, bh, sacc[1], 0, 0, 0);
        sacc[1] = __builtin_amdgcn_mfma_f32_16x16x32_bf16(ah1, bl, sacc[1], 0, 0, 0);
        sacc[1] = __builtin_amdgcn_mfma_f32_16x16x32_bf16(al1, bh, sacc[1], 0, 0, 0);
    }

    float mxv[8];
#pragma unroll
    for (int m = 0; m < 2; ++m)
#pragma unroll
        for (int r = 0; r < 4; ++r) {
            float v = sacc[m][r];
            v = fmaxf(v, __shfl_xor(v, 1)); v = fmaxf(v, __shfl_xor(v, 2));
            v = fmaxf(v, __shfl_xor(v, 4)); v = fmaxf(v, __shfl_xor(v, 8));
            mxv[m * 4 + r] = v;
        }
    if (li == 0) {
#pragma unroll
        for (int m = 0; m < 2; ++m)
#pragma unroll
            for (int r = 0; r < 4; ++r) xch[w][m * 16 + g * 4 + r] = mxv[m * 4 + r];
    }
    __syncthreads();
    float ev[8], sv[8];
#pragma unroll
    for (int m = 0; m < 2; ++m)
#pragma unroll
        for (int r = 0; r < 4; ++r) {
            int row = m * 16 + g * 4 + r;
            float mx = fmaxf(fmaxf(xch[0][row], xch[1][row]), fmaxf(xch[2][row], xch[3][row]));
            float e = __expf(sacc[m][r] - mx);
            ev[m * 4 + r] = e;
            float s = e;
            s += __shfl_xor(s, 1); s += __shfl_xor(s, 2);
            s += __shfl_xor(s, 4); s += __shfl_xor(s, 8);
            sv[m * 4 + r] = s;
        }
    __syncthreads();
    if (li == 0) {
#pragma unroll
        for (int m = 0; m < 2; ++m)
#pragma unroll
            for (int r = 0; r < 4; ++r) xch[w][m * 16 + g * 4 + r] = sv[m * 4 + r];
    }
    __syncthreads();
#pragma unroll
    for (int m = 0; m < 2; ++m)
#pragma unroll
        for (int r = 0; r < 4; ++r) {
            int row = m * 16 + g * 4 + r;
            float tot = xch[0][row] + xch[1][row] + xch[2][row] + xch[3][row];
            float wv = ev[m * 4 + r] / tot;
            ushort_t hi, lo; split_bf16(wv, hi, lo);
            int idx = row * 64 + (slot ^ ((row & 7) << 3));
            Wp[0][idx] = hi; Wp[1][idx] = lo;
        }
    __syncthreads();

    bf16x8 wah[2][2], wal[2][2];
#pragma unroll
    for (int m = 0; m < 2; ++m)
#pragma unroll
        for (int kt2 = 0; kt2 < 2; ++kt2) {
            int row = m * 16 + li;
            int k8 = kt2 * 4 + g;
            int idx = row * 64 + ((k8 * 8) ^ ((row & 7) << 3));
            wah[m][kt2] = *(const bf16x8*)&Wp[0][idx];
            wal[m][kt2] = *(const bf16x8*)&Wp[1][idx];
        }
    float lp = 0.f;
#pragma unroll 2
    for (int nfi = 0; nfi < 12; ++nfi) {
        int col = w * 192 + nfi * 16 + li;
        f32x4 pacc[2];
        pacc[0] = (f32x4){0.f,0.f,0.f,0.f}; pacc[1] = (f32x4){0.f,0.f,0.f,0.f};
#pragma unroll
        for (int kt2 = 0; kt2 < 2; ++kt2) {
            bf16x8 bh = *(const bf16x8*)(MThi + (size_t)col * 64 + kt2 * 32 + g * 8);
            bf16x8 bl = *(const bf16x8*)(MTlo + (size_t)col * 64 + kt2 * 32 + g * 8);
#pragma unroll
            for (int m = 0; m < 2; ++m) {
                pacc[m] = __builtin_amdgcn_mfma_f32_16x16x32_bf16(wah[m][kt2], bh, pacc[m], 0, 0, 0);
                pacc[m] = __builtin_amdgcn_mfma_f32_16x16x32_bf16(wah[m][kt2], bl, pacc[m], 0, 0, 0);
                pacc[m] = __builtin_amdgcn_mfma_f32_16x16x32_bf16(wal[m][kt2], bh, pacc[m], 0, 0, 0);
            }
        }
#pragma unroll
        for (int m = 0; m < 2; ++m)
#pragma unroll
            for (int r = 0; r < 4; ++r) {
                int row = base + m * 16 + g * 4 + r;
                float v = pacc[m][r] * (1.f / 64.f);
                float x = nf[(size_t)row * 768 + col];
                re[(size_t)row * 768 + col] = v;
                float d = x - v;
                lp = fmaf(d, d, lp);
            }
    }
    for (int o = 32; o; o >>= 1) lp += __shfl_xor(lp, o);
    if (l == 0) lred[w] = lp;
    __syncthreads();
    if (tid == 0) atomicAdd(lossac, lred[0] + lred[1] + lred[2] + lred[3]);
}

__global__ void k_loss_final(const float* __restrict__ acc, float* __restrict__ out, float invn) {
    if (threadIdx.x == 0 && blockIdx.x == 0) out[0] = acc[0] * invn;
}

// ---------------- launch ----------------
extern "C" void kernel_launch(void* const* d_in, const int* in_sizes, int n_in,
                              void* d_out, int out_size, void* d_ws, size_t ws_size,
                              hipStream_t stream) {
    const float* feature  = (const float*)d_in[0];
    const float* ppr      = (const float*)d_in[1];
    const float* edge_attr= (const float*)d_in[2];
    const float* Ws       = (const float*)d_in[3];
    const float* bs       = (const float*)d_in[4];
    const float* W1       = (const float*)d_in[5];
    const float* b1       = (const float*)d_in[6];
    const float* prelu_a  = (const float*)d_in[7];
    const float* W2       = (const float*)d_in[8];
    const float* b2       = (const float*)d_in[9];
    const float* Wp1      = (const float*)d_in[10];
    const float* bp1      = (const float*)d_in[11];
    const float* Wp2      = (const float*)d_in[12];
    const float* bp2      = (const float*)d_in[13];
    const float* memory   = (const float*)d_in[14];
    const int*   edge_index = (const int*)d_in[15];
    const int*   batch_ids  = (const int*)d_in[16];

    const int E = in_sizes[15] / 2;
    const int N = in_sizes[0] / DIN;
    const int* col = edge_index + E;

    char* ws = (char*)d_ws;
    ushort_t* Xhi  = (ushort_t*)(ws + OFF_XHI);
    ushort_t* Xlo  = (ushort_t*)(ws + OFF_XLO);
    ushort_t* Hhi  = (ushort_t*)(ws + OFF_HHI);
    ushort_t* Hlo  = (ushort_t*)(ws + OFF_HLO);
    float*    nf   = (float*)   (ws + OFF_NF);
    ushort_t* NFhi = (ushort_t*)(ws + OFF_NFHI);
    ushort_t* NFlo = (ushort_t*)(ws + OFF_NFLO);
    ushort_t* W1Thi= (ushort_t*)(ws + OFF_W1THI);
    ushort_t* W2Thi= (ushort_t*)(ws + OFF_W2THI);
    ushort_t* Mhi  = (ushort_t*)(ws + OFF_MHI);
    ushort_t* Mlo  = (ushort_t*)(ws + OFF_MLO);
    ushort_t* MThi = (ushort_t*)(ws + OFF_MTHI);
    ushort_t* MTlo = (ushort_t*)(ws + OFF_MTLO);
    int*   bucket = (int*)(ws + OFF_BUCKET);
    int*   counts = (int*)(ws + OFF_COUNTS);
    int*   gstart = (int*)(ws + OFF_GSTART);
    int*   gend   = (int*)(ws + OFF_GEND);
    float* lossac = (float*)(ws + OFF_LOSS);
    float* gfeatT = (float*)(ws + OFF_GFEAT);
    float* t1T    = (float*)(ws + OFF_T1);

    float* out_pooled = (float*)d_out;
    float* out_re     = (float*)d_out + NGRAPH * DOUT;
    float* out_loss   = (float*)d_out + NGRAPH * DOUT + (size_t)N * DOUT;

    (void)hipMemsetAsync(ws + ZERO_OFF, 0, ZERO_BYTES, stream);

    k_prep<<<1416, 256, 0, stream>>>(W1, W2, memory, W1Thi, W2Thi,
                                     MThi, MTlo, Mhi, Mlo);

    k_fill_bucket<<<1024 + (NNODES + 255) / 256, 256, 0, stream>>>(
        col, counts, bucket, E, batch_ids, gstart, gend, N);
    k_aggregate<<<N, 192, 0, stream>>>(feature, edge_attr, ppr, Ws, bs, bucket, counts, Xhi, Xlo);

    k_gemm_mfma<1, 1><<<dim3(DHID / 128, N / 64), 256, 0, stream>>>(
        Xhi, Xlo, W1Thi, b1, prelu_a, nullptr, Hhi, Hlo, N, DHID, XDIM);
    k_gemm_mfma<0, 2><<<dim3(DOUT / 128, N / 64), 256, 0, stream>>>(
        Hhi, Hlo, W2Thi, b2, nullptr, nf, NFhi, NFlo, N, DOUT, DHID);

    k_pool<<<dim3(NGRAPH, 6), 128, 0, stream>>>(nf, gstart, gend, gfeatT);

    k_mlp_t<2><<<768, 256, 0, stream>>>(gfeatT, Wp1, bp1, t1T, nullptr);
    k_mlp_t<0><<<768, 256, 0, stream>>>(t1T, Wp2, bp2, nullptr, out_pooled);

    k_attn<<<N / 32, 256, 0, stream>>>(NFhi, NFlo, Mhi, Mlo, MThi, MTlo, nf, out_re, lossac);
    k_loss_final<<<1, 64, 0, stream>>>(lossac, out_loss, 1.f / (float)((size_t)N * DOUT));
}

// Round 10
// 360.613 us; speedup vs baseline: 1.2971x; 1.0537x over previous
//
#include <hip/hip_runtime.h>
#include <hip/hip_bf16.h>
#include <math.h>

typedef unsigned short ushort_t;
typedef short bf16x8 __attribute__((ext_vector_type(8)));
typedef float f32x4 __attribute__((ext_vector_type(4)));

#define NNODES   8192
#define DIN      768
#define DSTRUCT  32
#define XDIM     800
#define DHID     768
#define DOUT     768
#define MEMK     64
#define NGRAPH   64
#define BUCKET_CAP 128

// ---------------- workspace layout (bytes) ----------------
#define OFF_XBF     0u
#define OFF_HBF     (OFF_XBF  + 8192u*800u*2u)
#define OFF_NF      (OFF_HBF  + 8192u*768u*2u)     // f32 [8192][768]
#define OFF_NFHI    (OFF_NF   + 8192u*768u*4u)
#define OFF_NFLO    (OFF_NFHI + 8192u*768u*2u)
#define OFF_W1T     (OFF_NFLO + 8192u*768u*2u)
#define OFF_W2T     (OFF_W1T  + 768u*800u*2u)
#define OFF_MHI     (OFF_W2T  + 768u*768u*2u)
#define OFF_MLO     (OFF_MHI  + 64u*768u*2u)
#define OFF_MTHI    (OFF_MLO  + 64u*768u*2u)
#define OFF_MTLO    (OFF_MTHI + 768u*64u*2u)
#define OFF_BUCKET  (OFF_MTLO + 768u*64u*2u)
#define OFF_COUNTS  (OFF_BUCKET + 8192u*BUCKET_CAP*4u)
#define OFF_GSTART  (OFF_COUNTS + 8192u*4u)
#define OFF_GEND    (OFF_GSTART + 256u)
#define OFF_LOSS    (OFF_GEND + 256u)
#define OFF_GFEAT   (OFF_LOSS + 256u)          // gfeatT [768][64] f32
#define OFF_T1      (OFF_GFEAT + 768u*64u*4u)  // t1T [768][64] f32
#define ZERO_OFF    OFF_COUNTS
#define ZERO_BYTES  (8192u*4u + 256u + 256u + 256u)

// ---------------- helpers ----------------
__device__ __forceinline__ ushort_t bf_rne(float f) {
    unsigned u = __float_as_uint(f);
    return (ushort_t)((u + 0x7FFFu + ((u >> 16) & 1u)) >> 16);
}
__device__ __forceinline__ void split_bf16(float f, ushort_t& hi, ushort_t& lo) {
    ushort_t h = bf_rne(f);
    float fh = __uint_as_float(((unsigned)h) << 16);
    hi = h;
    lo = bf_rne(f - fh);
}
__device__ __forceinline__ void gld16(const void* g, void* l) {
    __builtin_amdgcn_global_load_lds(
        (const __attribute__((address_space(1))) unsigned int*)g,
        (__attribute__((address_space(3))) unsigned int*)l, 16, 0, 0);
}

// ---------------- fused prep: transpose W1/W2 (bf16), mem planes ----------------
template<bool WLO>
__device__ __forceinline__ void dsplit(const float* __restrict__ W,
                                       ushort_t* __restrict__ Thi, ushort_t* __restrict__ Tlo,
                                       int K, int N, int bx, int by) {
    __shared__ float tile[32][33];
    int n0 = bx * 32, k0 = by * 32;
    int tx = threadIdx.x & 31, ty = threadIdx.x >> 5;
#pragma unroll
    for (int i = 0; i < 4; ++i) {
        int k = ty + i * 8;
        tile[k][tx] = W[(size_t)(k0 + k) * N + n0 + tx];
    }
    __syncthreads();
#pragma unroll
    for (int i = 0; i < 4; ++i) {
        int nn = ty + i * 8;
        float v = tile[tx][nn];
        ushort_t hi, lo; split_bf16(v, hi, lo);
        Thi[(size_t)(n0 + nn) * K + k0 + tx] = hi;
        if (WLO) Tlo[(size_t)(n0 + nn) * K + k0 + tx] = lo;
    }
}

__global__ __launch_bounds__(256) void k_prep(
    const float* __restrict__ W1, const float* __restrict__ W2, const float* __restrict__ mem,
    ushort_t* __restrict__ W1T, ushort_t* __restrict__ W2T,
    ushort_t* __restrict__ MThi, ushort_t* __restrict__ MTlo,
    ushort_t* __restrict__ Mhi, ushort_t* __restrict__ Mlo) {
    int b = blockIdx.x;
    if (b < 600)       dsplit<false>(W1, W1T, nullptr, XDIM, DHID, b % 24, b / 24);
    else if (b < 1176) dsplit<false>(W2, W2T, nullptr, DHID, DOUT, (b - 600) % 24, (b - 600) / 24);
    else if (b < 1224) dsplit<true>(mem, MThi, MTlo, MEMK, DOUT, (b - 1176) % 24, (b - 1176) / 24);
    else {
        int i = (b - 1224) * 256 + threadIdx.x;
        if (i < MEMK * 768) {
            ushort_t h, l; split_bf16(mem[i], h, l);
            Mhi[i] = h; Mlo[i] = l;
        }
    }
}

// ---------------- CSR build + graph boundaries (fused) ----------------
__global__ void k_fill_bucket(const int* __restrict__ col, int* __restrict__ counts,
                              int* __restrict__ bucket, int E,
                              const int* __restrict__ batch, int* __restrict__ gstart,
                              int* __restrict__ gend, int n) {
    if (blockIdx.x < 1024) {
        for (int e = blockIdx.x * blockDim.x + threadIdx.x; e < E; e += 1024 * blockDim.x) {
            int c = col[e];
            if ((unsigned)c < (unsigned)NNODES) {
                int p = atomicAdd(&counts[c], 1);
                if (p < BUCKET_CAP) bucket[c * BUCKET_CAP + p] = e;
            }
        }
    } else {
        int i = (blockIdx.x - 1024) * 256 + threadIdx.x;
        if (i >= n) return;
        int b = batch[i];
        if ((unsigned)b >= (unsigned)NGRAPH) return;
        if (i == 0 || batch[i - 1] != b) gstart[b] = i;
        if (i == n - 1 || batch[i + 1] != b) gend[b] = i + 1;
    }
}

// ---------------- aggregate edges -> X bf16 ----------------
__global__ __launch_bounds__(192) void k_aggregate(
    const float* __restrict__ feature, const float* __restrict__ edge_attr,
    const float* __restrict__ ppr, const float* __restrict__ Ws, const float* __restrict__ bs,
    const int* __restrict__ bucket, const int* __restrict__ counts,
    ushort_t* __restrict__ Xbf) {
    int n = blockIdx.x;
    int t = threadIdx.x;
    const float4* frow = (const float4*)(feature + (size_t)n * DIN);
    float4 acc = frow[t];
    int deg = min(counts[n], BUCKET_CAP);
    const int* bk = bucket + n * BUCKET_CAP;
    for (int j = 0; j < deg; ++j) {
        int e = bk[j];
        float4 v = ((const float4*)(edge_attr + (size_t)e * DIN))[t];
        acc.x += v.x; acc.y += v.y; acc.z += v.z; acc.w += v.w;
    }
    ushort4 h4;
    h4.x = bf_rne(acc.x); h4.y = bf_rne(acc.y);
    h4.z = bf_rne(acc.z); h4.w = bf_rne(acc.w);
    *(ushort4*)(Xbf + (size_t)n * XDIM + t * 4) = h4;
    if (t < DSTRUCT / 4) {
        float p = ppr[n];
        int k = t * 4;
        ushort4 sh;
        sh.x = bf_rne(fmaxf(p * Ws[k+0] + bs[k+0], 0.f));
        sh.y = bf_rne(fmaxf(p * Ws[k+1] + bs[k+1], 0.f));
        sh.z = bf_rne(fmaxf(p * Ws[k+2] + bs[k+2], 0.f));
        sh.w = bf_rne(fmaxf(p * Ws[k+3] + bs[k+3], 0.f));
        *(ushort4*)(Xbf + (size_t)n * XDIM + DIN + k) = sh;
    }
}

// ---------------- single-pass bf16 MFMA GEMM ----------------
// C[M][N] = act(A @ B^T + bias);  A [M][K] bf16, BT [N][K] bf16
// BM=64 BN=128 BK=32, 256 thr = 4 waves (2M x 2N), wave tile 32x64.
// LDS per buf (ushort offsets): A[64][32] @0, B[128][32] @2048.  12KB/buf, dbuf 24KB.
// Staging 64B-granular: 4 consecutive lanes cover one row's 32 k-elems contiguously.
#define L_B   2048
#define L_BUF 6144

template<int ACT, int OUTMODE>   // ACT: 0 none, 1 prelu ; OUTMODE: 1 bf16 plane, 2 f32+hi/lo planes
__global__ __launch_bounds__(256) void k_gemm_mfma(
    const ushort_t* __restrict__ A, const ushort_t* __restrict__ B,
    const float* __restrict__ bias, const float* __restrict__ act_p,
    float* __restrict__ Cf, ushort_t* __restrict__ Cbf,
    ushort_t* __restrict__ Chi, ushort_t* __restrict__ Clo,
    int M, int N, int K) {
    __shared__ ushort_t lds[2 * L_BUF];
    int tid = threadIdx.x;
    int l = tid & 63, w = tid >> 6;

    int nbx = N / 128;
    int nwg = nbx * (M / 64);
    int bid = blockIdx.y * nbx + blockIdx.x;
    int q = nwg >> 3;
    int nb = (bid & 7) * q + (bid >> 3);
    int bx = nb % nbx, by = nb / nbx;
    int m0 = by * 64, n0 = bx * 128;

    int wm = w >> 1, wn = w & 1;

    f32x4 acc[2][4];
#pragma unroll
    for (int m = 0; m < 2; ++m)
#pragma unroll
        for (int n = 0; n < 4; ++n) acc[m][n] = (f32x4){0.f, 0.f, 0.f, 0.f};

    // staging: lane l covers row (w*16 + l/4), 16B chunk (l&3) of the 64B row
    int srow = w * 16 + (l >> 2);
    int sc   = (l & 3) * 8;
    const ushort_t* ag  = A + (size_t)(m0 + srow) * K + sc;
    const ushort_t* bg0 = B + (size_t)(n0 + srow) * K + sc;
    const ushort_t* bg1 = B + (size_t)(n0 + 64 + srow) * K + sc;

    int NT = K / 32;

    {
        ushort_t* b = lds;
        gld16(ag,  b + w * 512);
        gld16(bg0, b + L_B + w * 512);
        gld16(bg1, b + L_B + 2048 + w * 512);
    }

    int c0 = l >> 4;            // kchunk 0..3
    int arow = wm * 32 + (l & 15);
    int bcol = wn * 64 + (l & 15);

    for (int kt = 0; kt < NT; ++kt) {
        int cur = kt & 1;
        __syncthreads();
        if (kt + 1 < NT) {
            int ko = (kt + 1) * 32;
            ushort_t* b = lds + (cur ^ 1) * L_BUF;
            gld16(ag + ko,  b + w * 512);
            gld16(bg0 + ko, b + L_B + w * 512);
            gld16(bg1 + ko, b + L_B + 2048 + w * 512);
        }
        const ushort_t* cb = lds + cur * L_BUF;
        bf16x8 ah[2], bh[4];
#pragma unroll
        for (int m = 0; m < 2; ++m)
            ah[m] = *(const bf16x8*)(cb + (arow + m * 16) * 32 + c0 * 8);
#pragma unroll
        for (int n = 0; n < 4; ++n)
            bh[n] = *(const bf16x8*)(cb + L_B + (bcol + n * 16) * 32 + c0 * 8);
#pragma unroll
        for (int m = 0; m < 2; ++m)
#pragma unroll
            for (int n = 0; n < 4; ++n)
                acc[m][n] = __builtin_amdgcn_mfma_f32_16x16x32_bf16(ah[m], bh[n], acc[m][n], 0, 0, 0);
    }

    float ap = (ACT == 1) ? *act_p : 0.f;
#pragma unroll
    for (int m = 0; m < 2; ++m)
#pragma unroll
        for (int n = 0; n < 4; ++n) {
            int col = n0 + wn * 64 + n * 16 + (l & 15);
            float bv = bias[col];
#pragma unroll
            for (int r = 0; r < 4; ++r) {
                int row = m0 + wm * 32 + m * 16 + (l >> 4) * 4 + r;
                float x = acc[m][n][r] + bv;
                if (ACT == 1) x = x > 0.f ? x : ap * x;
                if (OUTMODE == 1) {
                    Cbf[(size_t)row * N + col] = bf_rne(x);
                } else {
                    ushort_t hi, lo; split_bf16(x, hi, lo);
                    Chi[(size_t)row * N + col] = hi;
                    Clo[(size_t)row * N + col] = lo;
                    Cf[(size_t)row * N + col] = x;
                }
            }
        }
}

// ---------------- scatter-mean pooling (f32 nf) -> gfeatT [768][64] ----------------
__global__ __launch_bounds__(128) void k_pool(const float* __restrict__ nf,
                                              const int* __restrict__ gstart, const int* __restrict__ gend,
                                              float* __restrict__ gfeatT) {
    int g = blockIdx.x, d = blockIdx.y * 128 + threadIdx.x;
    int s = gstart[g], e = gend[g];
    float a = 0.f;
    for (int n = s; n < e; ++n) a += nf[(size_t)n * DOUT + d];
    gfeatT[(size_t)d * 64 + g] = a / fmaxf((float)(e - s), 1.f);
}

// ---------------- pooled MLP, transpose-fed ----------------
template<int ACT>   // 2: tanh, write OutT[n][m] ; 0: none, write OutR[m][n]
__global__ __launch_bounds__(256) void k_mlp_t(const float* __restrict__ AT, const float* __restrict__ B,
                                               const float* __restrict__ bias,
                                               float* __restrict__ OutT, float* __restrict__ OutR) {
    __shared__ float red[4][64];
    int n = blockIdx.x;
    int l = threadIdx.x & 63, qw = threadIdx.x >> 6;
    float s = 0.f;
    const float* a = AT + l;
    const float* b = B + n;
#pragma unroll 8
    for (int k = qw * 192; k < qw * 192 + 192; ++k)
        s = fmaf(a[k * 64], b[k * 768], s);
    red[qw][l] = s;
    __syncthreads();
    if (threadIdx.x < 64) {
        float v = red[0][l] + red[1][l] + red[2][l] + red[3][l] + bias[n];
        if (ACT == 2) { v = tanhf(v); OutT[n * 64 + l] = v; }
        else OutR[(size_t)l * 768 + n] = v;
    }
}

// ---------------- fused MFMA attention: scores -> softmax -> PV + loss ----------------
__global__ __launch_bounds__(256) void k_attn(
    const ushort_t* __restrict__ NFhi, const ushort_t* __restrict__ NFlo,
    const ushort_t* __restrict__ Mhi,  const ushort_t* __restrict__ Mlo,
    const ushort_t* __restrict__ MThi, const ushort_t* __restrict__ MTlo,
    const float* __restrict__ nf, float* __restrict__ re, float* __restrict__ lossac) {
    __shared__ ushort_t Ah[96 * 32 * 8];
    __shared__ ushort_t Al[96 * 32 * 8];
    __shared__ ushort_t Wp[2][32 * 64];
    __shared__ float xch[4][32];
    __shared__ float lred[4];
    int tid = threadIdx.x, l = tid & 63, w = tid >> 6;
    int g = l >> 4, li = l & 15;
    int base = blockIdx.x * 32;

    for (int i = w * 12; i < w * 12 + 12; ++i) {
        int kc = i * 2 + (l >> 5), row = l & 31;
        gld16(NFhi + (size_t)(base + row) * 768 + kc * 8, Ah + i * 512);
        gld16(NFlo + (size_t)(base + row) * 768 + kc * 8, Al + i * 512);
    }
    __syncthreads();

    f32x4 sacc[2];
    sacc[0] = (f32x4){0.f,0.f,0.f,0.f}; sacc[1] = (f32x4){0.f,0.f,0.f,0.f};
    int slot = w * 16 + li;
#pragma unroll 4
    for (int kt = 0; kt < 24; ++kt) {
        bf16x8 ah0 = *(const bf16x8*)(Ah + (kt * 4 + g) * 256 + li * 8);
        bf16x8 ah1 = *(const bf16x8*)(Ah + (kt * 4 + g) * 256 + (li + 16) * 8);
        bf16x8 al0 = *(const bf16x8*)(Al + (kt * 4 + g) * 256 + li * 8);
        bf16x8 al1 = *(const bf16x8*)(Al + (kt * 4 + g) * 256 + (li + 16) * 8);
        bf16x8 bh  = *(const bf16x8*)(Mhi + (size_t)slot * 768 + kt * 32 + g * 8);
        bf16x8 bl  = *(const bf16x8*)(Mlo + (size_t)slot * 768 + kt * 32 + g * 8);
        sacc[0] = __builtin_amdgcn_mfma_f32_16x16x32_bf16(ah0, bh, sacc[0], 0, 0, 0);
        sacc[0] = __builtin_amdgcn_mfma_f32_16x16x32_bf16(ah0, bl, sacc[0], 0, 0, 0);
        sacc[0] = __builtin_amdgcn_mfma_f32_16x16x32_bf16(al0, bh, sacc[0], 0, 0, 0);
        sacc[1] = __builtin_amdgcn_mfma_f32_16x16x32_bf16(ah1, bh, sacc[1], 0, 0, 0);
        sacc[1] = __builtin_amdgcn_mfma_f32_16x16x32_bf16(ah1, bl, sacc[1], 0, 0, 0);
        sacc[1] = __builtin_amdgcn_mfma_f32_16x16x32_bf16(al1, bh, sacc[1], 0, 0, 0);
    }

    float mxv[8];
#pragma unroll
    for (int m = 0; m < 2; ++m)
#pragma unroll
        for (int r = 0; r < 4; ++r) {
            float v = sacc[m][r];
            v = fmaxf(v, __shfl_xor(v, 1)); v = fmaxf(v, __shfl_xor(v, 2));
            v = fmaxf(v, __shfl_xor(v, 4)); v = fmaxf(v, __shfl_xor(v, 8));
            mxv[m * 4 + r] = v;
        }
    if (li == 0) {
#pragma unroll
        for (int m = 0; m < 2; ++m)
#pragma unroll
            for (int r = 0; r < 4; ++r) xch[w][m * 16 + g * 4 + r] = mxv[m * 4 + r];
    }
    __syncthreads();
    float ev[8], sv[8];
#pragma unroll
    for (int m = 0; m < 2; ++m)
#pragma unroll
        for (int r = 0; r < 4; ++r) {
            int row = m * 16 + g * 4 + r;
            float mx = fmaxf(fmaxf(xch[0][row], xch[1][row]), fmaxf(xch[2][row], xch[3][row]));
            float e = __expf(sacc[m][r] - mx);
            ev[m * 4 + r] = e;
            float s = e;
            s += __shfl_xor(s, 1); s += __shfl_xor(s, 2);
            s += __shfl_xor(s, 4); s += __shfl_xor(s, 8);
            sv[m * 4 + r] = s;
        }
    __syncthreads();
    if (li == 0) {
#pragma unroll
        for (int m = 0; m < 2; ++m)
#pragma unroll
            for (int r = 0; r < 4; ++r) xch[w][m * 16 + g * 4 + r] = sv[m * 4 + r];
    }
    __syncthreads();
#pragma unroll
    for (int m = 0; m < 2; ++m)
#pragma unroll
        for (int r = 0; r < 4; ++r) {
            int row = m * 16 + g * 4 + r;
            float tot = xch[0][row] + xch[1][row] + xch[2][row] + xch[3][row];
            float wv = ev[m * 4 + r] / tot;
            ushort_t hi, lo; split_bf16(wv, hi, lo);
            int idx = row * 64 + (slot ^ ((row & 7) << 3));
            Wp[0][idx] = hi; Wp[1][idx] = lo;
        }
    __syncthreads();

    bf16x8 wah[2][2], wal[2][2];
#pragma unroll
    for (int m = 0; m < 2; ++m)
#pragma unroll
        for (int kt2 = 0; kt2 < 2; ++kt2) {
            int row = m * 16 + li;
            int k8 = kt2 * 4 + g;
            int idx = row * 64 + ((k8 * 8) ^ ((row & 7) << 3));
            wah[m][kt2] = *(const bf16x8*)&Wp[0][idx];
            wal[m][kt2] = *(const bf16x8*)&Wp[1][idx];
        }
    float lp = 0.f;
#pragma unroll 2
    for (int nfi = 0; nfi < 12; ++nfi) {
        int col = w * 192 + nfi * 16 + li;
        f32x4 pacc[2];
        pacc[0] = (f32x4){0.f,0.f,0.f,0.f}; pacc[1] = (f32x4){0.f,0.f,0.f,0.f};
#pragma unroll
        for (int kt2 = 0; kt2 < 2; ++kt2) {
            bf16x8 bh = *(const bf16x8*)(MThi + (size_t)col * 64 + kt2 * 32 + g * 8);
            bf16x8 bl = *(const bf16x8*)(MTlo + (size_t)col * 64 + kt2 * 32 + g * 8);
#pragma unroll
            for (int m = 0; m < 2; ++m) {
                pacc[m] = __builtin_amdgcn_mfma_f32_16x16x32_bf16(wah[m][kt2], bh, pacc[m], 0, 0, 0);
                pacc[m] = __builtin_amdgcn_mfma_f32_16x16x32_bf16(wah[m][kt2], bl, pacc[m], 0, 0, 0);
                pacc[m] = __builtin_amdgcn_mfma_f32_16x16x32_bf16(wal[m][kt2], bh, pacc[m], 0, 0, 0);
            }
        }
#pragma unroll
        for (int m = 0; m < 2; ++m)
#pragma unroll
            for (int r = 0; r < 4; ++r) {
                int row = base + m * 16 + g * 4 + r;
                float v = pacc[m][r] * (1.f / 64.f);
                float x = nf[(size_t)row * 768 + col];
                re[(size_t)row * 768 + col] = v;
                float d = x - v;
                lp = fmaf(d, d, lp);
            }
    }
    for (int o = 32; o; o >>= 1) lp += __shfl_xor(lp, o);
    if (l == 0) lred[w] = lp;
    __syncthreads();
    if (tid == 0) atomicAdd(lossac, lred[0] + lred[1] + lred[2] + lred[3]);
}

__global__ void k_loss_final(const float* __restrict__ acc, float* __restrict__ out, float invn) {
    if (threadIdx.x == 0 && blockIdx.x == 0) out[0] = acc[0] * invn;
}

// ---------------- launch ----------------
extern "C" void kernel_launch(void* const* d_in, const int* in_sizes, int n_in,
                              void* d_out, int out_size, void* d_ws, size_t ws_size,
                              hipStream_t stream) {
    const float* feature  = (const float*)d_in[0];
    const float* ppr      = (const float*)d_in[1];
    const float* edge_attr= (const float*)d_in[2];
    const float* Ws       = (const float*)d_in[3];
    const float* bs       = (const float*)d_in[4];
    const float* W1       = (const float*)d_in[5];
    const float* b1       = (const float*)d_in[6];
    const float* prelu_a  = (const float*)d_in[7];
    const float* W2       = (const float*)d_in[8];
    const float* b2       = (const float*)d_in[9];
    const float* Wp1      = (const float*)d_in[10];
    const float* bp1      = (const float*)d_in[11];
    const float* Wp2      = (const float*)d_in[12];
    const float* bp2      = (const float*)d_in[13];
    const float* memory   = (const float*)d_in[14];
    const int*   edge_index = (const int*)d_in[15];
    const int*   batch_ids  = (const int*)d_in[16];

    const int E = in_sizes[15] / 2;
    const int N = in_sizes[0] / DIN;
    const int* col = edge_index + E;

    char* ws = (char*)d_ws;
    ushort_t* Xbf  = (ushort_t*)(ws + OFF_XBF);
    ushort_t* Hbf  = (ushort_t*)(ws + OFF_HBF);
    float*    nf   = (float*)   (ws + OFF_NF);
    ushort_t* NFhi = (ushort_t*)(ws + OFF_NFHI);
    ushort_t* NFlo = (ushort_t*)(ws + OFF_NFLO);
    ushort_t* W1T  = (ushort_t*)(ws + OFF_W1T);
    ushort_t* W2T  = (ushort_t*)(ws + OFF_W2T);
    ushort_t* Mhi  = (ushort_t*)(ws + OFF_MHI);
    ushort_t* Mlo  = (ushort_t*)(ws + OFF_MLO);
    ushort_t* MThi = (ushort_t*)(ws + OFF_MTHI);
    ushort_t* MTlo = (ushort_t*)(ws + OFF_MTLO);
    int*   bucket = (int*)(ws + OFF_BUCKET);
    int*   counts = (int*)(ws + OFF_COUNTS);
    int*   gstart = (int*)(ws + OFF_GSTART);
    int*   gend   = (int*)(ws + OFF_GEND);
    float* lossac = (float*)(ws + OFF_LOSS);
    float* gfeatT = (float*)(ws + OFF_GFEAT);
    float* t1T    = (float*)(ws + OFF_T1);

    float* out_pooled = (float*)d_out;
    float* out_re     = (float*)d_out + NGRAPH * DOUT;
    float* out_loss   = (float*)d_out + NGRAPH * DOUT + (size_t)N * DOUT;

    (void)hipMemsetAsync(ws + ZERO_OFF, 0, ZERO_BYTES, stream);

    k_prep<<<1416, 256, 0, stream>>>(W1, W2, memory, W1T, W2T, MThi, MTlo, Mhi, Mlo);

    k_fill_bucket<<<1024 + (NNODES + 255) / 256, 256, 0, stream>>>(
        col, counts, bucket, E, batch_ids, gstart, gend, N);
    k_aggregate<<<N, 192, 0, stream>>>(feature, edge_attr, ppr, Ws, bs, bucket, counts, Xbf);

    k_gemm_mfma<1, 1><<<dim3(DHID / 128, N / 64), 256, 0, stream>>>(
        Xbf, W1T, b1, prelu_a, nullptr, Hbf, nullptr, nullptr, N, DHID, XDIM);
    k_gemm_mfma<0, 2><<<dim3(DOUT / 128, N / 64), 256, 0, stream>>>(
        Hbf, W2T, b2, nullptr, nf, nullptr, NFhi, NFlo, N, DOUT, DHID);

    k_pool<<<dim3(NGRAPH, 6), 128, 0, stream>>>(nf, gstart, gend, gfeatT);

    k_mlp_t<2><<<768, 256, 0, stream>>>(gfeatT, Wp1, bp1, t1T, nullptr);
    k_mlp_t<0><<<768, 256, 0, stream>>>(t1T, Wp2, bp2, nullptr, out_pooled);

    k_attn<<<N / 32, 256, 0, stream>>>(NFhi, NFlo, Mhi, Mlo, MThi, MTlo, nf, out_re, lossac);
    k_loss_final<<<1, 64, 0, stream>>>(lossac, out_loss, 1.f / (float)((size_t)N * DOUT));
}

// Round 11
// 354.556 us; speedup vs baseline: 1.3193x; 1.0171x over previous
//
#include <hip/hip_runtime.h>
#include <hip/hip_bf16.h>
#include <math.h>

typedef unsigned short ushort_t;
typedef short bf16x8 __attribute__((ext_vector_type(8)));
typedef float f32x4 __attribute__((ext_vector_type(4)));

#define NNODES   8192
#define DIN      768
#define DSTRUCT  32
#define XDIM     800
#define DHID     768
#define DOUT     768
#define MEMK     64
#define NGRAPH   64
#define BUCKET_CAP 128

// ---------------- workspace layout (bytes) ----------------
#define OFF_XBF     0u
#define OFF_HBF     (OFF_XBF  + 8192u*800u*2u)
#define OFF_NF      (OFF_HBF  + 8192u*768u*2u)     // f32 [8192][768]
#define OFF_NFHI    (OFF_NF   + 8192u*768u*4u)
#define OFF_NFLO    (OFF_NFHI + 8192u*768u*2u)
#define OFF_W1T     (OFF_NFLO + 8192u*768u*2u)
#define OFF_W2T     (OFF_W1T  + 768u*800u*2u)
#define OFF_MHI     (OFF_W2T  + 768u*768u*2u)
#define OFF_MLO     (OFF_MHI  + 64u*768u*2u)
#define OFF_MTHI    (OFF_MLO  + 64u*768u*2u)
#define OFF_MTLO    (OFF_MTHI + 768u*64u*2u)
#define OFF_BUCKET  (OFF_MTLO + 768u*64u*2u)
#define OFF_COUNTS  (OFF_BUCKET + 8192u*BUCKET_CAP*4u)
#define OFF_GSTART  (OFF_COUNTS + 8192u*4u)
#define OFF_GEND    (OFF_GSTART + 256u)
#define OFF_LOSS    (OFF_GEND + 256u)
#define OFF_GFEAT   (OFF_LOSS + 256u)          // gfeatT [768][64] f32
#define OFF_T1      (OFF_GFEAT + 768u*64u*4u)  // t1T [768][64] f32
#define ZERO_OFF    OFF_COUNTS
#define ZERO_BYTES  (8192u*4u + 256u + 256u + 256u)

// ---------------- helpers ----------------
__device__ __forceinline__ ushort_t bf_rne(float f) {
    unsigned u = __float_as_uint(f);
    return (ushort_t)((u + 0x7FFFu + ((u >> 16) & 1u)) >> 16);
}
__device__ __forceinline__ void split_bf16(float f, ushort_t& hi, ushort_t& lo) {
    ushort_t h = bf_rne(f);
    float fh = __uint_as_float(((unsigned)h) << 16);
    hi = h;
    lo = bf_rne(f - fh);
}
__device__ __forceinline__ void gld16(const void* g, void* l) {
    __builtin_amdgcn_global_load_lds(
        (const __attribute__((address_space(1))) unsigned int*)g,
        (__attribute__((address_space(3))) unsigned int*)l, 16, 0, 0);
}

// ---------------- fused prep: transpose W1/W2 (bf16), mem planes ----------------
template<bool WLO>
__device__ __forceinline__ void dsplit(const float* __restrict__ W,
                                       ushort_t* __restrict__ Thi, ushort_t* __restrict__ Tlo,
                                       int K, int N, int bx, int by) {
    __shared__ float tile[32][33];
    int n0 = bx * 32, k0 = by * 32;
    int tx = threadIdx.x & 31, ty = threadIdx.x >> 5;
#pragma unroll
    for (int i = 0; i < 4; ++i) {
        int k = ty + i * 8;
        tile[k][tx] = W[(size_t)(k0 + k) * N + n0 + tx];
    }
    __syncthreads();
#pragma unroll
    for (int i = 0; i < 4; ++i) {
        int nn = ty + i * 8;
        float v = tile[tx][nn];
        ushort_t hi, lo; split_bf16(v, hi, lo);
        Thi[(size_t)(n0 + nn) * K + k0 + tx] = hi;
        if (WLO) Tlo[(size_t)(n0 + nn) * K + k0 + tx] = lo;
    }
}

__global__ __launch_bounds__(256) void k_prep(
    const float* __restrict__ W1, const float* __restrict__ W2, const float* __restrict__ mem,
    ushort_t* __restrict__ W1T, ushort_t* __restrict__ W2T,
    ushort_t* __restrict__ MThi, ushort_t* __restrict__ MTlo,
    ushort_t* __restrict__ Mhi, ushort_t* __restrict__ Mlo) {
    int b = blockIdx.x;
    if (b < 600)       dsplit<false>(W1, W1T, nullptr, XDIM, DHID, b % 24, b / 24);
    else if (b < 1176) dsplit<false>(W2, W2T, nullptr, DHID, DOUT, (b - 600) % 24, (b - 600) / 24);
    else if (b < 1224) dsplit<true>(mem, MThi, MTlo, MEMK, DOUT, (b - 1176) % 24, (b - 1176) / 24);
    else {
        int i = (b - 1224) * 256 + threadIdx.x;
        if (i < MEMK * 768) {
            ushort_t h, l; split_bf16(mem[i], h, l);
            Mhi[i] = h; Mlo[i] = l;
        }
    }
}

// ---------------- CSR build + graph boundaries (fused) ----------------
__global__ void k_fill_bucket(const int* __restrict__ col, int* __restrict__ counts,
                              int* __restrict__ bucket, int E,
                              const int* __restrict__ batch, int* __restrict__ gstart,
                              int* __restrict__ gend, int n) {
    if (blockIdx.x < 1024) {
        for (int e = blockIdx.x * blockDim.x + threadIdx.x; e < E; e += 1024 * blockDim.x) {
            int c = col[e];
            if ((unsigned)c < (unsigned)NNODES) {
                int p = atomicAdd(&counts[c], 1);
                if (p < BUCKET_CAP) bucket[c * BUCKET_CAP + p] = e;
            }
        }
    } else {
        int i = (blockIdx.x - 1024) * 256 + threadIdx.x;
        if (i >= n) return;
        int b = batch[i];
        if ((unsigned)b >= (unsigned)NGRAPH) return;
        if (i == 0 || batch[i - 1] != b) gstart[b] = i;
        if (i == n - 1 || batch[i + 1] != b) gend[b] = i + 1;
    }
}

// ---------------- aggregate edges -> X bf16 ----------------
__global__ __launch_bounds__(192) void k_aggregate(
    const float* __restrict__ feature, const float* __restrict__ edge_attr,
    const float* __restrict__ ppr, const float* __restrict__ Ws, const float* __restrict__ bs,
    const int* __restrict__ bucket, const int* __restrict__ counts,
    ushort_t* __restrict__ Xbf) {
    int n = blockIdx.x;
    int t = threadIdx.x;
    const float4* frow = (const float4*)(feature + (size_t)n * DIN);
    float4 acc = frow[t];
    int deg = min(counts[n], BUCKET_CAP);
    const int* bk = bucket + n * BUCKET_CAP;
    for (int j = 0; j < deg; ++j) {
        int e = bk[j];
        float4 v = ((const float4*)(edge_attr + (size_t)e * DIN))[t];
        acc.x += v.x; acc.y += v.y; acc.z += v.z; acc.w += v.w;
    }
    ushort4 h4;
    h4.x = bf_rne(acc.x); h4.y = bf_rne(acc.y);
    h4.z = bf_rne(acc.z); h4.w = bf_rne(acc.w);
    *(ushort4*)(Xbf + (size_t)n * XDIM + t * 4) = h4;
    if (t < DSTRUCT / 4) {
        float p = ppr[n];
        int k = t * 4;
        ushort4 sh;
        sh.x = bf_rne(fmaxf(p * Ws[k+0] + bs[k+0], 0.f));
        sh.y = bf_rne(fmaxf(p * Ws[k+1] + bs[k+1], 0.f));
        sh.z = bf_rne(fmaxf(p * Ws[k+2] + bs[k+2], 0.f));
        sh.w = bf_rne(fmaxf(p * Ws[k+3] + bs[k+3], 0.f));
        *(ushort4*)(Xbf + (size_t)n * XDIM + DIN + k) = sh;
    }
}

// ---------------- single-pass bf16 MFMA GEMM, 128x128 tile (m97 structure) ----------------
// C[M][N] = act(A @ B^T + bias);  A [M][K] bf16, BT [N][K] bf16
// BM=128 BN=128 BK=32, 256 thr = 4 waves (2M x 2N), wave tile 64x64 (4x4 frags).
// LDS per buf (ushort offsets): A[128][32] @0, B[128][32] @4096.  16KB/buf, dbuf 32KB.
// Staging 64B-granular: 4 consecutive lanes cover one row's 32 k-elems contiguously;
// wave w stages A rows w*32..+31 and B rows w*32..+31 (2 gld16 each).
#define L_B   4096
#define L_BUF 8192

template<int ACT, int OUTMODE>   // ACT: 0 none, 1 prelu ; OUTMODE: 1 bf16 plane, 2 f32+hi/lo planes
__global__ __launch_bounds__(256) void k_gemm_mfma(
    const ushort_t* __restrict__ A, const ushort_t* __restrict__ B,
    const float* __restrict__ bias, const float* __restrict__ act_p,
    float* __restrict__ Cf, ushort_t* __restrict__ Cbf,
    ushort_t* __restrict__ Chi, ushort_t* __restrict__ Clo,
    int M, int N, int K) {
    __shared__ ushort_t lds[2 * L_BUF];
    int tid = threadIdx.x;
    int l = tid & 63, w = tid >> 6;

    int nbx = N / 128;
    int nwg = nbx * (M / 128);
    int bid = blockIdx.y * nbx + blockIdx.x;
    int q = nwg >> 3;
    int nb = (bid & 7) * q + (bid >> 3);
    int bx = nb % nbx, by = nb / nbx;
    int m0 = by * 128, n0 = bx * 128;

    int wm = w >> 1, wn = w & 1;

    f32x4 acc[4][4];
#pragma unroll
    for (int m = 0; m < 4; ++m)
#pragma unroll
        for (int n = 0; n < 4; ++n) acc[m][n] = (f32x4){0.f, 0.f, 0.f, 0.f};

    // staging: wave w covers rows w*32..w*32+31 of A and of B; lane: row +(l>>2), chunk (l&3)*8
    int srow = w * 32 + (l >> 2);
    int sc   = (l & 3) * 8;
    const ushort_t* ag0 = A + (size_t)(m0 + srow) * K + sc;
    const ushort_t* ag1 = ag0 + (size_t)16 * K;
    const ushort_t* bg0 = B + (size_t)(n0 + srow) * K + sc;
    const ushort_t* bg1 = bg0 + (size_t)16 * K;

    int NT = K / 32;

    {
        ushort_t* b = lds;
        gld16(ag0, b + w * 1024);
        gld16(ag1, b + w * 1024 + 512);
        gld16(bg0, b + L_B + w * 1024);
        gld16(bg1, b + L_B + w * 1024 + 512);
    }

    int c0 = l >> 4;            // kchunk 0..3
    int li = l & 15;

    for (int kt = 0; kt < NT; ++kt) {
        int cur = kt & 1;
        __syncthreads();
        if (kt + 1 < NT) {
            int ko = (kt + 1) * 32;
            ushort_t* b = lds + (cur ^ 1) * L_BUF;
            gld16(ag0 + ko, b + w * 1024);
            gld16(ag1 + ko, b + w * 1024 + 512);
            gld16(bg0 + ko, b + L_B + w * 1024);
            gld16(bg1 + ko, b + L_B + w * 1024 + 512);
        }
        const ushort_t* cb = lds + cur * L_BUF;
        bf16x8 ah[4], bh[4];
#pragma unroll
        for (int m = 0; m < 4; ++m)
            ah[m] = *(const bf16x8*)(cb + (wm * 64 + m * 16 + li) * 32 + c0 * 8);
#pragma unroll
        for (int n = 0; n < 4; ++n)
            bh[n] = *(const bf16x8*)(cb + L_B + (wn * 64 + n * 16 + li) * 32 + c0 * 8);
#pragma unroll
        for (int m = 0; m < 4; ++m)
#pragma unroll
            for (int n = 0; n < 4; ++n)
                acc[m][n] = __builtin_amdgcn_mfma_f32_16x16x32_bf16(ah[m], bh[n], acc[m][n], 0, 0, 0);
    }

    float ap = (ACT == 1) ? *act_p : 0.f;
#pragma unroll
    for (int m = 0; m < 4; ++m)
#pragma unroll
        for (int n = 0; n < 4; ++n) {
            int col = n0 + wn * 64 + n * 16 + li;
            float bv = bias[col];
#pragma unroll
            for (int r = 0; r < 4; ++r) {
                int row = m0 + wm * 64 + m * 16 + c0 * 4 + r;
                float x = acc[m][n][r] + bv;
                if (ACT == 1) x = x > 0.f ? x : ap * x;
                if (OUTMODE == 1) {
                    Cbf[(size_t)row * N + col] = bf_rne(x);
                } else {
                    ushort_t hi, lo; split_bf16(x, hi, lo);
                    Chi[(size_t)row * N + col] = hi;
                    Clo[(size_t)row * N + col] = lo;
                    Cf[(size_t)row * N + col] = x;
                }
            }
        }
}

// ---------------- scatter-mean pooling (f32 nf) -> gfeatT [768][64] ----------------
__global__ __launch_bounds__(128) void k_pool(const float* __restrict__ nf,
                                              const int* __restrict__ gstart, const int* __restrict__ gend,
                                              float* __restrict__ gfeatT) {
    int g = blockIdx.x, d = blockIdx.y * 128 + threadIdx.x;
    int s = gstart[g], e = gend[g];
    float a = 0.f;
    for (int n = s; n < e; ++n) a += nf[(size_t)n * DOUT + d];
    gfeatT[(size_t)d * 64 + g] = a / fmaxf((float)(e - s), 1.f);
}

// ---------------- pooled MLP, transpose-fed ----------------
template<int ACT>   // 2: tanh, write OutT[n][m] ; 0: none, write OutR[m][n]
__global__ __launch_bounds__(256) void k_mlp_t(const float* __restrict__ AT, const float* __restrict__ B,
                                               const float* __restrict__ bias,
                                               float* __restrict__ OutT, float* __restrict__ OutR) {
    __shared__ float red[4][64];
    int n = blockIdx.x;
    int l = threadIdx.x & 63, qw = threadIdx.x >> 6;
    float s = 0.f;
    const float* a = AT + l;
    const float* b = B + n;
#pragma unroll 8
    for (int k = qw * 192; k < qw * 192 + 192; ++k)
        s = fmaf(a[k * 64], b[k * 768], s);
    red[qw][l] = s;
    __syncthreads();
    if (threadIdx.x < 64) {
        float v = red[0][l] + red[1][l] + red[2][l] + red[3][l] + bias[n];
        if (ACT == 2) { v = tanhf(v); OutT[n * 64 + l] = v; }
        else OutR[(size_t)l * 768 + n] = v;
    }
}

// ---------------- fused MFMA attention: scores -> softmax -> PV + loss ----------------
__global__ __launch_bounds__(256) void k_attn(
    const ushort_t* __restrict__ NFhi, const ushort_t* __restrict__ NFlo,
    const ushort_t* __restrict__ Mhi,  const ushort_t* __restrict__ Mlo,
    const ushort_t* __restrict__ MThi, const ushort_t* __restrict__ MTlo,
    const float* __restrict__ nf, float* __restrict__ re, float* __restrict__ lossac) {
    __shared__ ushort_t Ah[96 * 32 * 8];
    __shared__ ushort_t Al[96 * 32 * 8];
    __shared__ ushort_t Wp[2][32 * 64];
    __shared__ float xch[4][32];
    __shared__ float lred[4];
    int tid = threadIdx.x, l = tid & 63, w = tid >> 6;
    int g = l >> 4, li = l & 15;
    int base = blockIdx.x * 32;

    for (int i = w * 12; i < w * 12 + 12; ++i) {
        int kc = i * 2 + (l >> 5), row = l & 31;
        gld16(NFhi + (size_t)(base + row) * 768 + kc * 8, Ah + i * 512);
        gld16(NFlo + (size_t)(base + row) * 768 + kc * 8, Al + i * 512);
    }
    __syncthreads();

    f32x4 sacc[2];
    sacc[0] = (f32x4){0.f,0.f,0.f,0.f}; sacc[1] = (f32x4){0.f,0.f,0.f,0.f};
    int slot = w * 16 + li;
#pragma unroll 4
    for (int kt = 0; kt < 24; ++kt) {
        bf16x8 ah0 = *(const bf16x8*)(Ah + (kt * 4 + g) * 256 + li * 8);
        bf16x8 ah1 = *(const bf16x8*)(Ah + (kt * 4 + g) * 256 + (li + 16) * 8);
        bf16x8 al0 = *(const bf16x8*)(Al + (kt * 4 + g) * 256 + li * 8);
        bf16x8 al1 = *(const bf16x8*)(Al + (kt * 4 + g) * 256 + (li + 16) * 8);
        bf16x8 bh  = *(const bf16x8*)(Mhi + (size_t)slot * 768 + kt * 32 + g * 8);
        bf16x8 bl  = *(const bf16x8*)(Mlo + (size_t)slot * 768 + kt * 32 + g * 8);
        sacc[0] = __builtin_amdgcn_mfma_f32_16x16x32_bf16(ah0, bh, sacc[0], 0, 0, 0);
        sacc[0] = __builtin_amdgcn_mfma_f32_16x16x32_bf16(ah0, bl, sacc[0], 0, 0, 0);
        sacc[0] = __builtin_amdgcn_mfma_f32_16x16x32_bf16(al0, bh, sacc[0], 0, 0, 0);
        sacc[1] = __builtin_amdgcn_mfma_f32_16x16x32_bf16(ah1, bh, sacc[1], 0, 0, 0);
        sacc[1] = __builtin_amdgcn_mfma_f32_16x16x32_bf16(ah1, bl, sacc[1], 0, 0, 0);
        sacc[1] = __builtin_amdgcn_mfma_f32_16x16x32_bf16(al1, bh, sacc[1], 0, 0, 0);
    }

    float mxv[8];
#pragma unroll
    for (int m = 0; m < 2; ++m)
#pragma unroll
        for (int r = 0; r < 4; ++r) {
            float v = sacc[m][r];
            v = fmaxf(v, __shfl_xor(v, 1)); v = fmaxf(v, __shfl_xor(v, 2));
            v = fmaxf(v, __shfl_xor(v, 4)); v = fmaxf(v, __shfl_xor(v, 8));
            mxv[m * 4 + r] = v;
        }
    if (li == 0) {
#pragma unroll
        for (int m = 0; m < 2; ++m)
#pragma unroll
            for (int r = 0; r < 4; ++r) xch[w][m * 16 + g * 4 + r] = mxv[m * 4 + r];
    }
    __syncthreads();
    float ev[8], sv[8];
#pragma unroll
    for (int m = 0; m < 2; ++m)
#pragma unroll
        for (int r = 0; r < 4; ++r) {
            int row = m * 16 + g * 4 + r;
            float mx = fmaxf(fmaxf(xch[0][row], xch[1][row]), fmaxf(xch[2][row], xch[3][row]));
            float e = __expf(sacc[m][r] - mx);
            ev[m * 4 + r] = e;
            float s = e;
            s += __shfl_xor(s, 1); s += __shfl_xor(s, 2);
            s += __shfl_xor(s, 4); s += __shfl_xor(s, 8);
            sv[m * 4 + r] = s;
        }
    __syncthreads();
    if (li == 0) {
#pragma unroll
        for (int m = 0; m < 2; ++m)
#pragma unroll
            for (int r = 0; r < 4; ++r) xch[w][m * 16 + g * 4 + r] = sv[m * 4 + r];
    }
    __syncthreads();
#pragma unroll
    for (int m = 0; m < 2; ++m)
#pragma unroll
        for (int r = 0; r < 4; ++r) {
            int row = m * 16 + g * 4 + r;
            float tot = xch[0][row] + xch[1][row] + xch[2][row] + xch[3][row];
            float wv = ev[m * 4 + r] / tot;
            ushort_t hi, lo; split_bf16(wv, hi, lo);
            int idx = row * 64 + (slot ^ ((row & 7) << 3));
            Wp[0][idx] = hi; Wp[1][idx] = lo;
        }
    __syncthreads();

    bf16x8 wah[2][2], wal[2][2];
#pragma unroll
    for (int m = 0; m < 2; ++m)
#pragma unroll
        for (int kt2 = 0; kt2 < 2; ++kt2) {
            int row = m * 16 + li;
            int k8 = kt2 * 4 + g;
            int idx = row * 64 + ((k8 * 8) ^ ((row & 7) << 3));
            wah[m][kt2] = *(const bf16x8*)&Wp[0][idx];
            wal[m][kt2] = *(const bf16x8*)&Wp[1][idx];
        }
    float lp = 0.f;
#pragma unroll 2
    for (int nfi = 0; nfi < 12; ++nfi) {
        int col = w * 192 + nfi * 16 + li;
        f32x4 pacc[2];
        pacc[0] = (f32x4){0.f,0.f,0.f,0.f}; pacc[1] = (f32x4){0.f,0.f,0.f,0.f};
#pragma unroll
        for (int kt2 = 0; kt2 < 2; ++kt2) {
            bf16x8 bh = *(const bf16x8*)(MThi + (size_t)col * 64 + kt2 * 32 + g * 8);
            bf16x8 bl = *(const bf16x8*)(MTlo + (size_t)col * 64 + kt2 * 32 + g * 8);
#pragma unroll
            for (int m = 0; m < 2; ++m) {
                pacc[m] = __builtin_amdgcn_mfma_f32_16x16x32_bf16(wah[m][kt2], bh, pacc[m], 0, 0, 0);
                pacc[m] = __builtin_amdgcn_mfma_f32_16x16x32_bf16(wah[m][kt2], bl, pacc[m], 0, 0, 0);
                pacc[m] = __builtin_amdgcn_mfma_f32_16x16x32_bf16(wal[m][kt2], bh, pacc[m], 0, 0, 0);
            }
        }
#pragma unroll
        for (int m = 0; m < 2; ++m)
#pragma unroll
            for (int r = 0; r < 4; ++r) {
                int row = base + m * 16 + g * 4 + r;
                float v = pacc[m][r] * (1.f / 64.f);
                float x = nf[(size_t)row * 768 + col];
                re[(size_t)row * 768 + col] = v;
                float d = x - v;
                lp = fmaf(d, d, lp);
            }
    }
    for (int o = 32; o; o >>= 1) lp += __shfl_xor(lp, o);
    if (l == 0) lred[w] = lp;
    __syncthreads();
    if (tid == 0) atomicAdd(lossac, lred[0] + lred[1] + lred[2] + lred[3]);
}

__global__ void k_loss_final(const float* __restrict__ acc, float* __restrict__ out, float invn) {
    if (threadIdx.x == 0 && blockIdx.x == 0) out[0] = acc[0] * invn;
}

// ---------------- launch ----------------
extern "C" void kernel_launch(void* const* d_in, const int* in_sizes, int n_in,
                              void* d_out, int out_size, void* d_ws, size_t ws_size,
                              hipStream_t stream) {
    const float* feature  = (const float*)d_in[0];
    const float* ppr      = (const float*)d_in[1];
    const float* edge_attr= (const float*)d_in[2];
    const float* Ws       = (const float*)d_in[3];
    const float* bs       = (const float*)d_in[4];
    const float* W1       = (const float*)d_in[5];
    const float* b1       = (const float*)d_in[6];
    const float* prelu_a  = (const float*)d_in[7];
    const float* W2       = (const float*)d_in[8];
    const float* b2       = (const float*)d_in[9];
    const float* Wp1      = (const float*)d_in[10];
    const float* bp1      = (const float*)d_in[11];
    const float* Wp2      = (const float*)d_in[12];
    const float* bp2      = (const float*)d_in[13];
    const float* memory   = (const float*)d_in[14];
    const int*   edge_index = (const int*)d_in[15];
    const int*   batch_ids  = (const int*)d_in[16];

    const int E = in_sizes[15] / 2;
    const int N = in_sizes[0] / DIN;
    const int* col = edge_index + E;

    char* ws = (char*)d_ws;
    ushort_t* Xbf  = (ushort_t*)(ws + OFF_XBF);
    ushort_t* Hbf  = (ushort_t*)(ws + OFF_HBF);
    float*    nf   = (float*)   (ws + OFF_NF);
    ushort_t* NFhi = (ushort_t*)(ws + OFF_NFHI);
    ushort_t* NFlo = (ushort_t*)(ws + OFF_NFLO);
    ushort_t* W1T  = (ushort_t*)(ws + OFF_W1T);
    ushort_t* W2T  = (ushort_t*)(ws + OFF_W2T);
    ushort_t* Mhi  = (ushort_t*)(ws + OFF_MHI);
    ushort_t* Mlo  = (ushort_t*)(ws + OFF_MLO);
    ushort_t* MThi = (ushort_t*)(ws + OFF_MTHI);
    ushort_t* MTlo = (ushort_t*)(ws + OFF_MTLO);
    int*   bucket = (int*)(ws + OFF_BUCKET);
    int*   counts = (int*)(ws + OFF_COUNTS);
    int*   gstart = (int*)(ws + OFF_GSTART);
    int*   gend   = (int*)(ws + OFF_GEND);
    float* lossac = (float*)(ws + OFF_LOSS);
    float* gfeatT = (float*)(ws + OFF_GFEAT);
    float* t1T    = (float*)(ws + OFF_T1);

    float* out_pooled = (float*)d_out;
    float* out_re     = (float*)d_out + NGRAPH * DOUT;
    float* out_loss   = (float*)d_out + NGRAPH * DOUT + (size_t)N * DOUT;

    (void)hipMemsetAsync(ws + ZERO_OFF, 0, ZERO_BYTES, stream);

    k_prep<<<1416, 256, 0, stream>>>(W1, W2, memory, W1T, W2T, MThi, MTlo, Mhi, Mlo);

    k_fill_bucket<<<1024 + (NNODES + 255) / 256, 256, 0, stream>>>(
        col, counts, bucket, E, batch_ids, gstart, gend, N);
    k_aggregate<<<N, 192, 0, stream>>>(feature, edge_attr, ppr, Ws, bs, bucket, counts, Xbf);

    k_gemm_mfma<1, 1><<<dim3(DHID / 128, N / 128), 256, 0, stream>>>(
        Xbf, W1T, b1, prelu_a, nullptr, Hbf, nullptr, nullptr, N, DHID, XDIM);
    k_gemm_mfma<0, 2><<<dim3(DOUT / 128, N / 128), 256, 0, stream>>>(
        Hbf, W2T, b2, nullptr, nf, nullptr, NFhi, NFlo, N, DOUT, DHID);

    k_pool<<<dim3(NGRAPH, 6), 128, 0, stream>>>(nf, gstart, gend, gfeatT);

    k_mlp_t<2><<<768, 256, 0, stream>>>(gfeatT, Wp1, bp1, t1T, nullptr);
    k_mlp_t<0><<<768, 256, 0, stream>>>(t1T, Wp2, bp2, nullptr, out_pooled);

    k_attn<<<N / 32, 256, 0, stream>>>(NFhi, NFlo, Mhi, Mlo, MThi, MTlo, nf, out_re, lossac);
    k_loss_final<<<1, 64, 0, stream>>>(lossac, out_loss, 1.f / (float)((size_t)N * DOUT));
}

// Round 12
// 352.334 us; speedup vs baseline: 1.3276x; 1.0063x over previous
//
#include <hip/hip_runtime.h>
#include <hip/hip_bf16.h>
#include <math.h>

typedef unsigned short ushort_t;
typedef short bf16x8 __attribute__((ext_vector_type(8)));
typedef float f32x4 __attribute__((ext_vector_type(4)));

#define NNODES   8192
#define DIN      768
#define DSTRUCT  32
#define XDIM     800
#define DHID     768
#define DOUT     768
#define MEMK     64
#define NGRAPH   64
#define BUCKET_CAP 128

// ---------------- workspace layout (bytes) ----------------
#define OFF_XBF     0u
#define OFF_HBF     (OFF_XBF  + 8192u*800u*2u)
#define OFF_NF      (OFF_HBF  + 8192u*768u*2u)     // f32 [8192][768]
#define OFF_NFHI    (OFF_NF   + 8192u*768u*4u)
#define OFF_NFLO    (OFF_NFHI + 8192u*768u*2u)
#define OFF_W1T     (OFF_NFLO + 8192u*768u*2u)
#define OFF_W2T     (OFF_W1T  + 768u*800u*2u)
#define OFF_MHI     (OFF_W2T  + 768u*768u*2u)
#define OFF_MLO     (OFF_MHI  + 64u*768u*2u)
#define OFF_MTHI    (OFF_MLO  + 64u*768u*2u)
#define OFF_MTLO    (OFF_MTHI + 768u*64u*2u)
#define OFF_BUCKET  (OFF_MTLO + 768u*64u*2u)
#define OFF_COUNTS  (OFF_BUCKET + 8192u*BUCKET_CAP*4u)
#define OFF_GSTART  (OFF_COUNTS + 8192u*4u)
#define OFF_GEND    (OFF_GSTART + 256u)
#define OFF_LOSS    (OFF_GEND + 256u)
#define OFF_GFEAT   (OFF_LOSS + 256u)          // gfeatT [768][64] f32
#define OFF_T1      (OFF_GFEAT + 768u*64u*4u)  // t1T [768][64] f32
#define ZERO_OFF    OFF_COUNTS
#define ZERO_BYTES  (8192u*4u + 256u + 256u + 256u)

// ---------------- helpers ----------------
__device__ __forceinline__ ushort_t bf_rne(float f) {
    unsigned u = __float_as_uint(f);
    return (ushort_t)((u + 0x7FFFu + ((u >> 16) & 1u)) >> 16);
}
__device__ __forceinline__ void split_bf16(float f, ushort_t& hi, ushort_t& lo) {
    ushort_t h = bf_rne(f);
    float fh = __uint_as_float(((unsigned)h) << 16);
    hi = h;
    lo = bf_rne(f - fh);
}
__device__ __forceinline__ void gld16(const void* g, void* l) {
    __builtin_amdgcn_global_load_lds(
        (const __attribute__((address_space(1))) unsigned int*)g,
        (__attribute__((address_space(3))) unsigned int*)l, 16, 0, 0);
}

// ---------------- fused setup: W transposes + mem planes + CSR fill + boundaries ----------------
template<bool WLO>
__device__ __forceinline__ void dsplit(const float* __restrict__ W,
                                       ushort_t* __restrict__ Thi, ushort_t* __restrict__ Tlo,
                                       int K, int N, int bx, int by) {
    __shared__ float tile[32][33];
    int n0 = bx * 32, k0 = by * 32;
    int tx = threadIdx.x & 31, ty = threadIdx.x >> 5;
#pragma unroll
    for (int i = 0; i < 4; ++i) {
        int k = ty + i * 8;
        tile[k][tx] = W[(size_t)(k0 + k) * N + n0 + tx];
    }
    __syncthreads();
#pragma unroll
    for (int i = 0; i < 4; ++i) {
        int nn = ty + i * 8;
        float v = tile[tx][nn];
        ushort_t hi, lo; split_bf16(v, hi, lo);
        Thi[(size_t)(n0 + nn) * K + k0 + tx] = hi;
        if (WLO) Tlo[(size_t)(n0 + nn) * K + k0 + tx] = lo;
    }
}

__global__ __launch_bounds__(256) void k_setup(
    const float* __restrict__ W1, const float* __restrict__ W2, const float* __restrict__ mem,
    ushort_t* __restrict__ W1T, ushort_t* __restrict__ W2T,
    ushort_t* __restrict__ MThi, ushort_t* __restrict__ MTlo,
    ushort_t* __restrict__ Mhi, ushort_t* __restrict__ Mlo,
    const int* __restrict__ col, int* __restrict__ counts, int* __restrict__ bucket, int E,
    const int* __restrict__ batch, int* __restrict__ gstart, int* __restrict__ gend, int n) {
    int b = blockIdx.x;
    if (b < 600)       dsplit<false>(W1, W1T, nullptr, XDIM, DHID, b % 24, b / 24);
    else if (b < 1176) dsplit<false>(W2, W2T, nullptr, DHID, DOUT, (b - 600) % 24, (b - 600) / 24);
    else if (b < 1224) dsplit<true>(mem, MThi, MTlo, MEMK, DOUT, (b - 1176) % 24, (b - 1176) / 24);
    else if (b < 1416) {
        int i = (b - 1224) * 256 + threadIdx.x;
        if (i < MEMK * 768) {
            ushort_t h, l; split_bf16(mem[i], h, l);
            Mhi[i] = h; Mlo[i] = l;
        }
    } else if (b < 2440) {
        for (int e = (b - 1416) * 256 + threadIdx.x; e < E; e += 1024 * 256) {
            int c = col[e];
            if ((unsigned)c < (unsigned)NNODES) {
                int p = atomicAdd(&counts[c], 1);
                if (p < BUCKET_CAP) bucket[c * BUCKET_CAP + p] = e;
            }
        }
    } else {
        int i = (b - 2440) * 256 + threadIdx.x;
        if (i >= n) return;
        int bb = batch[i];
        if ((unsigned)bb >= (unsigned)NGRAPH) return;
        if (i == 0 || batch[i - 1] != bb) gstart[bb] = i;
        if (i == n - 1 || batch[i + 1] != bb) gend[bb] = i + 1;
    }
}

// ---------------- aggregate edges -> X bf16 ----------------
__global__ __launch_bounds__(192) void k_aggregate(
    const float* __restrict__ feature, const float* __restrict__ edge_attr,
    const float* __restrict__ ppr, const float* __restrict__ Ws, const float* __restrict__ bs,
    const int* __restrict__ bucket, const int* __restrict__ counts,
    ushort_t* __restrict__ Xbf) {
    int n = blockIdx.x;
    int t = threadIdx.x;
    const float4* frow = (const float4*)(feature + (size_t)n * DIN);
    float4 acc = frow[t];
    int deg = min(counts[n], BUCKET_CAP);
    const int* bk = bucket + n * BUCKET_CAP;
    for (int j = 0; j < deg; ++j) {
        int e = bk[j];
        float4 v = ((const float4*)(edge_attr + (size_t)e * DIN))[t];
        acc.x += v.x; acc.y += v.y; acc.z += v.z; acc.w += v.w;
    }
    ushort4 h4;
    h4.x = bf_rne(acc.x); h4.y = bf_rne(acc.y);
    h4.z = bf_rne(acc.z); h4.w = bf_rne(acc.w);
    *(ushort4*)(Xbf + (size_t)n * XDIM + t * 4) = h4;
    if (t < DSTRUCT / 4) {
        float p = ppr[n];
        int k = t * 4;
        ushort4 sh;
        sh.x = bf_rne(fmaxf(p * Ws[k+0] + bs[k+0], 0.f));
        sh.y = bf_rne(fmaxf(p * Ws[k+1] + bs[k+1], 0.f));
        sh.z = bf_rne(fmaxf(p * Ws[k+2] + bs[k+2], 0.f));
        sh.w = bf_rne(fmaxf(p * Ws[k+3] + bs[k+3], 0.f));
        *(ushort4*)(Xbf + (size_t)n * XDIM + DIN + k) = sh;
    }
}

// ---------------- single-pass bf16 MFMA GEMM, 128x128 tile (m97 structure) ----------------
#define L_B   4096
#define L_BUF 8192

template<int ACT, int OUTMODE>   // ACT: 0 none, 1 prelu ; OUTMODE: 1 bf16 plane, 2 f32+hi/lo planes
__global__ __launch_bounds__(256) void k_gemm_mfma(
    const ushort_t* __restrict__ A, const ushort_t* __restrict__ B,
    const float* __restrict__ bias, const float* __restrict__ act_p,
    float* __restrict__ Cf, ushort_t* __restrict__ Cbf,
    ushort_t* __restrict__ Chi, ushort_t* __restrict__ Clo,
    int M, int N, int K) {
    __shared__ ushort_t lds[2 * L_BUF];
    int tid = threadIdx.x;
    int l = tid & 63, w = tid >> 6;

    int nbx = N / 128;
    int nwg = nbx * (M / 128);
    int bid = blockIdx.y * nbx + blockIdx.x;
    int q = nwg >> 3;
    int nb = (bid & 7) * q + (bid >> 3);
    int bx = nb % nbx, by = nb / nbx;
    int m0 = by * 128, n0 = bx * 128;

    int wm = w >> 1, wn = w & 1;

    f32x4 acc[4][4];
#pragma unroll
    for (int m = 0; m < 4; ++m)
#pragma unroll
        for (int n = 0; n < 4; ++n) acc[m][n] = (f32x4){0.f, 0.f, 0.f, 0.f};

    int srow = w * 32 + (l >> 2);
    int sc   = (l & 3) * 8;
    const ushort_t* ag0 = A + (size_t)(m0 + srow) * K + sc;
    const ushort_t* ag1 = ag0 + (size_t)16 * K;
    const ushort_t* bg0 = B + (size_t)(n0 + srow) * K + sc;
    const ushort_t* bg1 = bg0 + (size_t)16 * K;

    int NT = K / 32;

    {
        ushort_t* b = lds;
        gld16(ag0, b + w * 1024);
        gld16(ag1, b + w * 1024 + 512);
        gld16(bg0, b + L_B + w * 1024);
        gld16(bg1, b + L_B + w * 1024 + 512);
    }

    int c0 = l >> 4;
    int li = l & 15;

    for (int kt = 0; kt < NT; ++kt) {
        int cur = kt & 1;
        __syncthreads();
        if (kt + 1 < NT) {
            int ko = (kt + 1) * 32;
            ushort_t* b = lds + (cur ^ 1) * L_BUF;
            gld16(ag0 + ko, b + w * 1024);
            gld16(ag1 + ko, b + w * 1024 + 512);
            gld16(bg0 + ko, b + L_B + w * 1024);
            gld16(bg1 + ko, b + L_B + w * 1024 + 512);
        }
        const ushort_t* cb = lds + cur * L_BUF;
        bf16x8 ah[4], bh[4];
#pragma unroll
        for (int m = 0; m < 4; ++m)
            ah[m] = *(const bf16x8*)(cb + (wm * 64 + m * 16 + li) * 32 + c0 * 8);
#pragma unroll
        for (int n = 0; n < 4; ++n)
            bh[n] = *(const bf16x8*)(cb + L_B + (wn * 64 + n * 16 + li) * 32 + c0 * 8);
#pragma unroll
        for (int m = 0; m < 4; ++m)
#pragma unroll
            for (int n = 0; n < 4; ++n)
                acc[m][n] = __builtin_amdgcn_mfma_f32_16x16x32_bf16(ah[m], bh[n], acc[m][n], 0, 0, 0);
    }

    float ap = (ACT == 1) ? *act_p : 0.f;
#pragma unroll
    for (int m = 0; m < 4; ++m)
#pragma unroll
        for (int n = 0; n < 4; ++n) {
            int col = n0 + wn * 64 + n * 16 + li;
            float bv = bias[col];
#pragma unroll
            for (int r = 0; r < 4; ++r) {
                int row = m0 + wm * 64 + m * 16 + c0 * 4 + r;
                float x = acc[m][n][r] + bv;
                if (ACT == 1) x = x > 0.f ? x : ap * x;
                if (OUTMODE == 1) {
                    Cbf[(size_t)row * N + col] = bf_rne(x);
                } else {
                    ushort_t hi, lo; split_bf16(x, hi, lo);
                    Chi[(size_t)row * N + col] = hi;
                    Clo[(size_t)row * N + col] = lo;
                    Cf[(size_t)row * N + col] = x;
                }
            }
        }
}

// ---------------- scatter-mean pooling (f32 nf) -> gfeatT [768][64] ----------------
__global__ __launch_bounds__(128) void k_pool(const float* __restrict__ nf,
                                              const int* __restrict__ gstart, const int* __restrict__ gend,
                                              float* __restrict__ gfeatT) {
    int g = blockIdx.x, d = blockIdx.y * 128 + threadIdx.x;
    int s = gstart[g], e = gend[g];
    float a = 0.f;
    for (int n = s; n < e; ++n) a += nf[(size_t)n * DOUT + d];
    gfeatT[(size_t)d * 64 + g] = a / fmaxf((float)(e - s), 1.f);
}

// ---------------- pooled MLP, transpose-fed ----------------
template<int ACT>   // 2: tanh, write OutT[n][m] ; 0: none, write OutR[m][n]
__global__ __launch_bounds__(256) void k_mlp_t(const float* __restrict__ AT, const float* __restrict__ B,
                                               const float* __restrict__ bias,
                                               float* __restrict__ OutT, float* __restrict__ OutR) {
    __shared__ float red[4][64];
    int n = blockIdx.x;
    int l = threadIdx.x & 63, qw = threadIdx.x >> 6;
    float s = 0.f;
    const float* a = AT + l;
    const float* b = B + n;
#pragma unroll 8
    for (int k = qw * 192; k < qw * 192 + 192; ++k)
        s = fmaf(a[k * 64], b[k * 768], s);
    red[qw][l] = s;
    __syncthreads();
    if (threadIdx.x < 64) {
        float v = red[0][l] + red[1][l] + red[2][l] + red[3][l] + bias[n];
        if (ACT == 2) { v = tanhf(v); OutT[n * 64 + l] = v; }
        else OutR[(size_t)l * 768 + n] = v;
    }
}

// ---------------- fused MFMA attention: scores -> softmax -> PV + loss ----------------
__global__ __launch_bounds__(256) void k_attn(
    const ushort_t* __restrict__ NFhi, const ushort_t* __restrict__ NFlo,
    const ushort_t* __restrict__ Mhi,  const ushort_t* __restrict__ Mlo,
    const ushort_t* __restrict__ MThi, const ushort_t* __restrict__ MTlo,
    const float* __restrict__ nf, float* __restrict__ re, float* __restrict__ lossac) {
    __shared__ ushort_t Ah[96 * 32 * 8];
    __shared__ ushort_t Al[96 * 32 * 8];
    __shared__ ushort_t Wp[2][32 * 64];
    __shared__ float xch[4][32];
    __shared__ float lred[4];
    int tid = threadIdx.x, l = tid & 63, w = tid >> 6;
    int g = l >> 4, li = l & 15;
    int base = blockIdx.x * 32;

    for (int i = w * 12; i < w * 12 + 12; ++i) {
        int kc = i * 2 + (l >> 5), row = l & 31;
        gld16(NFhi + (size_t)(base + row) * 768 + kc * 8, Ah + i * 512);
        gld16(NFlo + (size_t)(base + row) * 768 + kc * 8, Al + i * 512);
    }
    __syncthreads();

    f32x4 sacc[2];
    sacc[0] = (f32x4){0.f,0.f,0.f,0.f}; sacc[1] = (f32x4){0.f,0.f,0.f,0.f};
    int slot = w * 16 + li;
#pragma unroll 4
    for (int kt = 0; kt < 24; ++kt) {
        bf16x8 ah0 = *(const bf16x8*)(Ah + (kt * 4 + g) * 256 + li * 8);
        bf16x8 ah1 = *(const bf16x8*)(Ah + (kt * 4 + g) * 256 + (li + 16) * 8);
        bf16x8 al0 = *(const bf16x8*)(Al + (kt * 4 + g) * 256 + li * 8);
        bf16x8 al1 = *(const bf16x8*)(Al + (kt * 4 + g) * 256 + (li + 16) * 8);
        bf16x8 bh  = *(const bf16x8*)(Mhi + (size_t)slot * 768 + kt * 32 + g * 8);
        bf16x8 bl  = *(const bf16x8*)(Mlo + (size_t)slot * 768 + kt * 32 + g * 8);
        sacc[0] = __builtin_amdgcn_mfma_f32_16x16x32_bf16(ah0, bh, sacc[0], 0, 0, 0);
        sacc[0] = __builtin_amdgcn_mfma_f32_16x16x32_bf16(ah0, bl, sacc[0], 0, 0, 0);
        sacc[0] = __builtin_amdgcn_mfma_f32_16x16x32_bf16(al0, bh, sacc[0], 0, 0, 0);
        sacc[1] = __builtin_amdgcn_mfma_f32_16x16x32_bf16(ah1, bh, sacc[1], 0, 0, 0);
        sacc[1] = __builtin_amdgcn_mfma_f32_16x16x32_bf16(ah1, bl, sacc[1], 0, 0, 0);
        sacc[1] = __builtin_amdgcn_mfma_f32_16x16x32_bf16(al1, bh, sacc[1], 0, 0, 0);
    }

    float mxv[8];
#pragma unroll
    for (int m = 0; m < 2; ++m)
#pragma unroll
        for (int r = 0; r < 4; ++r) {
            float v = sacc[m][r];
            v = fmaxf(v, __shfl_xor(v, 1)); v = fmaxf(v, __shfl_xor(v, 2));
            v = fmaxf(v, __shfl_xor(v, 4)); v = fmaxf(v, __shfl_xor(v, 8));
            mxv[m * 4 + r] = v;
        }
    if (li == 0) {
#pragma unroll
        for (int m = 0; m < 2; ++m)
#pragma unroll
            for (int r = 0; r < 4; ++r) xch[w][m * 16 + g * 4 + r] = mxv[m * 4 + r];
    }
    __syncthreads();
    float ev[8], sv[8];
#pragma unroll
    for (int m = 0; m < 2; ++m)
#pragma unroll
        for (int r = 0; r < 4; ++r) {
            int row = m * 16 + g * 4 + r;
            float mx = fmaxf(fmaxf(xch[0][row], xch[1][row]), fmaxf(xch[2][row], xch[3][row]));
            float e = __expf(sacc[m][r] - mx);
            ev[m * 4 + r] = e;
            float s = e;
            s += __shfl_xor(s, 1); s += __shfl_xor(s, 2);
            s += __shfl_xor(s, 4); s += __shfl_xor(s, 8);
            sv[m * 4 + r] = s;
        }
    __syncthreads();
    if (li == 0) {
#pragma unroll
        for (int m = 0; m < 2; ++m)
#pragma unroll
            for (int r = 0; r < 4; ++r) xch[w][m * 16 + g * 4 + r] = sv[m * 4 + r];
    }
    __syncthreads();
#pragma unroll
    for (int m = 0; m < 2; ++m)
#pragma unroll
        for (int r = 0; r < 4; ++r) {
            int row = m * 16 + g * 4 + r;
            float tot = xch[0][row] + xch[1][row] + xch[2][row] + xch[3][row];
            float wv = ev[m * 4 + r] / tot;
            ushort_t hi, lo; split_bf16(wv, hi, lo);
            int idx = row * 64 + (slot ^ ((row & 7) << 3));
            Wp[0][idx] = hi; Wp[1][idx] = lo;
        }
    __syncthreads();

    bf16x8 wah[2][2], wal[2][2];
#pragma unroll
    for (int m = 0; m < 2; ++m)
#pragma unroll
        for (int kt2 = 0; kt2 < 2; ++kt2) {
            int row = m * 16 + li;
            int k8 = kt2 * 4 + g;
            int idx = row * 64 + ((k8 * 8) ^ ((row & 7) << 3));
            wah[m][kt2] = *(const bf16x8*)&Wp[0][idx];
            wal[m][kt2] = *(const bf16x8*)&Wp[1][idx];
        }
    float lp = 0.f;
#pragma unroll 2
    for (int nfi = 0; nfi < 12; ++nfi) {
        int col = w * 192 + nfi * 16 + li;
        f32x4 pacc[2];
        pacc[0] = (f32x4){0.f,0.f,0.f,0.f}; pacc[1] = (f32x4){0.f,0.f,0.f,0.f};
#pragma unroll
        for (int kt2 = 0; kt2 < 2; ++kt2) {
            bf16x8 bh = *(const bf16x8*)(MThi + (size_t)col * 64 + kt2 * 32 + g * 8);
            bf16x8 bl = *(const bf16x8*)(MTlo + (size_t)col * 64 + kt2 * 32 + g * 8);
#pragma unroll
            for (int m = 0; m < 2; ++m) {
                pacc[m] = __builtin_amdgcn_mfma_f32_16x16x32_bf16(wah[m][kt2], bh, pacc[m], 0, 0, 0);
                pacc[m] = __builtin_amdgcn_mfma_f32_16x16x32_bf16(wah[m][kt2], bl, pacc[m], 0, 0, 0);
                pacc[m] = __builtin_amdgcn_mfma_f32_16x16x32_bf16(wal[m][kt2], bh, pacc[m], 0, 0, 0);
            }
        }
#pragma unroll
        for (int m = 0; m < 2; ++m)
#pragma unroll
            for (int r = 0; r < 4; ++r) {
                int row = base + m * 16 + g * 4 + r;
                float v = pacc[m][r] * (1.f / 64.f);
                float x = nf[(size_t)row * 768 + col];
                re[(size_t)row * 768 + col] = v;
                float d = x - v;
                lp = fmaf(d, d, lp);
            }
    }
    for (int o = 32; o; o >>= 1) lp += __shfl_xor(lp, o);
    if (l == 0) lred[w] = lp;
    __syncthreads();
    if (tid == 0) atomicAdd(lossac, lred[0] + lred[1] + lred[2] + lred[3]);
}

__global__ void k_loss_final(const float* __restrict__ acc, float* __restrict__ out, float invn) {
    if (threadIdx.x == 0 && blockIdx.x == 0) out[0] = acc[0] * invn;
}

// ---------------- launch ----------------
extern "C" void kernel_launch(void* const* d_in, const int* in_sizes, int n_in,
                              void* d_out, int out_size, void* d_ws, size_t ws_size,
                              hipStream_t stream) {
    const float* feature  = (const float*)d_in[0];
    const float* ppr      = (const float*)d_in[1];
    const float* edge_attr= (const float*)d_in[2];
    const float* Ws       = (const float*)d_in[3];
    const float* bs       = (const float*)d_in[4];
    const float* W1       = (const float*)d_in[5];
    const float* b1       = (const float*)d_in[6];
    const float* prelu_a  = (const float*)d_in[7];
    const float* W2       = (const float*)d_in[8];
    const float* b2       = (const float*)d_in[9];
    const float* Wp1      = (const float*)d_in[10];
    const float* bp1      = (const float*)d_in[11];
    const float* Wp2      = (const float*)d_in[12];
    const float* bp2      = (const float*)d_in[13];
    const float* memory   = (const float*)d_in[14];
    const int*   edge_index = (const int*)d_in[15];
    const int*   batch_ids  = (const int*)d_in[16];

    const int E = in_sizes[15] / 2;
    const int N = in_sizes[0] / DIN;
    const int* col = edge_index + E;

    char* ws = (char*)d_ws;
    ushort_t* Xbf  = (ushort_t*)(ws + OFF_XBF);
    ushort_t* Hbf  = (ushort_t*)(ws + OFF_HBF);
    float*    nf   = (float*)   (ws + OFF_NF);
    ushort_t* NFhi = (ushort_t*)(ws + OFF_NFHI);
    ushort_t* NFlo = (ushort_t*)(ws + OFF_NFLO);
    ushort_t* W1T  = (ushort_t*)(ws + OFF_W1T);
    ushort_t* W2T  = (ushort_t*)(ws + OFF_W2T);
    ushort_t* Mhi  = (ushort_t*)(ws + OFF_MHI);
    ushort_t* Mlo  = (ushort_t*)(ws + OFF_MLO);
    ushort_t* MThi = (ushort_t*)(ws + OFF_MTHI);
    ushort_t* MTlo = (ushort_t*)(ws + OFF_MTLO);
    int*   bucket = (int*)(ws + OFF_BUCKET);
    int*   counts = (int*)(ws + OFF_COUNTS);
    int*   gstart = (int*)(ws + OFF_GSTART);
    int*   gend   = (int*)(ws + OFF_GEND);
    float* lossac = (float*)(ws + OFF_LOSS);
    float* gfeatT = (float*)(ws + OFF_GFEAT);
    float* t1T    = (float*)(ws + OFF_T1);

    float* out_pooled = (float*)d_out;
    float* out_re     = (float*)d_out + NGRAPH * DOUT;
    float* out_loss   = (float*)d_out + NGRAPH * DOUT + (size_t)N * DOUT;

    (void)hipMemsetAsync(ws + ZERO_OFF, 0, ZERO_BYTES, stream);

    k_setup<<<2440 + (NNODES + 255) / 256, 256, 0, stream>>>(
        W1, W2, memory, W1T, W2T, MThi, MTlo, Mhi, Mlo,
        col, counts, bucket, E, batch_ids, gstart, gend, N);

    k_aggregate<<<N, 192, 0, stream>>>(feature, edge_attr, ppr, Ws, bs, bucket, counts, Xbf);

    k_gemm_mfma<1, 1><<<dim3(DHID / 128, N / 128), 256, 0, stream>>>(
        Xbf, W1T, b1, prelu_a, nullptr, Hbf, nullptr, nullptr, N, DHID, XDIM);
    k_gemm_mfma<0, 2><<<dim3(DOUT / 128, N / 128), 256, 0, stream>>>(
        Hbf, W2T, b2, nullptr, nf, nullptr, NFhi, NFlo, N, DOUT, DHID);

    k_pool<<<dim3(NGRAPH, 6), 128, 0, stream>>>(nf, gstart, gend, gfeatT);

    k_mlp_t<2><<<768, 256, 0, stream>>>(gfeatT, Wp1, bp1, t1T, nullptr);
    k_mlp_t<0><<<768, 256, 0, stream>>>(t1T, Wp2, bp2, nullptr, out_pooled);

    k_attn<<<N / 32, 256, 0, stream>>>(NFhi, NFlo, Mhi, Mlo, MThi, MTlo, nf, out_re, lossac);
    k_loss_final<<<1, 64, 0, stream>>>(lossac, out_loss, 1.f / (float)((size_t)N * DOUT));
}

// Round 13
// 350.150 us; speedup vs baseline: 1.3359x; 1.0062x over previous
//
#include <hip/hip_runtime.h>
#include <hip/hip_bf16.h>
#include <math.h>

typedef unsigned short ushort_t;
typedef short bf16x8 __attribute__((ext_vector_type(8)));
typedef float f32x4 __attribute__((ext_vector_type(4)));

#define NNODES   8192
#define DIN      768
#define DSTRUCT  32
#define XDIM     800
#define DHID     768
#define DOUT     768
#define MEMK     64
#define NGRAPH   64
#define BUCKET_CAP 128

// ---------------- workspace layout (bytes) ----------------
#define OFF_XBF     0u
#define OFF_HBF     (OFF_XBF  + 8192u*800u*2u)
#define OFF_NF      (OFF_HBF  + 8192u*768u*2u)     // f32 [8192][768]
#define OFF_NFHI    (OFF_NF   + 8192u*768u*4u)
#define OFF_NFLO    (OFF_NFHI + 8192u*768u*2u)
#define OFF_W1T     (OFF_NFLO + 8192u*768u*2u)
#define OFF_W2T     (OFF_W1T  + 768u*800u*2u)
#define OFF_MHI     (OFF_W2T  + 768u*768u*2u)
#define OFF_MLO     (OFF_MHI  + 64u*768u*2u)
#define OFF_MTHI    (OFF_MLO  + 64u*768u*2u)
#define OFF_MTLO    (OFF_MTHI + 768u*64u*2u)
#define OFF_BUCKET  (OFF_MTLO + 768u*64u*2u)
#define OFF_COUNTS  (OFF_BUCKET + 8192u*BUCKET_CAP*4u)
#define OFF_GSTART  (OFF_COUNTS + 8192u*4u)
#define OFF_GEND    (OFF_GSTART + 256u)
#define OFF_LOSS    (OFF_GEND + 256u)
#define OFF_GFEAT   (OFF_LOSS + 256u)          // gfeatT [768][64] f32
#define OFF_T1      (OFF_GFEAT + 768u*64u*4u)  // t1T [768][64] f32
#define ZERO_OFF    OFF_COUNTS
#define ZERO_BYTES  (8192u*4u + 256u + 256u + 256u)

// ---------------- helpers ----------------
__device__ __forceinline__ ushort_t bf_rne(float f) {
    unsigned u = __float_as_uint(f);
    return (ushort_t)((u + 0x7FFFu + ((u >> 16) & 1u)) >> 16);
}
__device__ __forceinline__ void split_bf16(float f, ushort_t& hi, ushort_t& lo) {
    ushort_t h = bf_rne(f);
    float fh = __uint_as_float(((unsigned)h) << 16);
    hi = h;
    lo = bf_rne(f - fh);
}
__device__ __forceinline__ void gld16(const void* g, void* l) {
    __builtin_amdgcn_global_load_lds(
        (const __attribute__((address_space(1))) unsigned int*)g,
        (__attribute__((address_space(3))) unsigned int*)l, 16, 0, 0);
}

// ---------------- CSR fill + graph boundaries (precedes aggregate) ----------------
__global__ void k_csr(const int* __restrict__ col, int* __restrict__ counts,
                      int* __restrict__ bucket, int E,
                      const int* __restrict__ batch, int* __restrict__ gstart,
                      int* __restrict__ gend, int n) {
    if (blockIdx.x < 1024) {
        for (int e = blockIdx.x * blockDim.x + threadIdx.x; e < E; e += 1024 * blockDim.x) {
            int c = col[e];
            if ((unsigned)c < (unsigned)NNODES) {
                int p = atomicAdd(&counts[c], 1);
                if (p < BUCKET_CAP) bucket[c * BUCKET_CAP + p] = e;
            }
        }
    } else {
        int i = (blockIdx.x - 1024) * 256 + threadIdx.x;
        if (i >= n) return;
        int b = batch[i];
        if ((unsigned)b >= (unsigned)NGRAPH) return;
        if (i == 0 || batch[i - 1] != b) gstart[b] = i;
        if (i == n - 1 || batch[i + 1] != b) gend[b] = i + 1;
    }
}

// ---------------- weight prep (blocks 0..1415) + aggregate (blocks 1416+) ----------------
template<bool WLO>
__device__ __forceinline__ void dsplit(const float* __restrict__ W,
                                       ushort_t* __restrict__ Thi, ushort_t* __restrict__ Tlo,
                                       int K, int N, int bx, int by) {
    __shared__ float tile[32][33];
    int n0 = bx * 32, k0 = by * 32;
    int tx = threadIdx.x & 31, ty = threadIdx.x >> 5;
#pragma unroll
    for (int i = 0; i < 4; ++i) {
        int k = ty + i * 8;
        tile[k][tx] = W[(size_t)(k0 + k) * N + n0 + tx];
    }
    __syncthreads();
#pragma unroll
    for (int i = 0; i < 4; ++i) {
        int nn = ty + i * 8;
        float v = tile[tx][nn];
        ushort_t hi, lo; split_bf16(v, hi, lo);
        Thi[(size_t)(n0 + nn) * K + k0 + tx] = hi;
        if (WLO) Tlo[(size_t)(n0 + nn) * K + k0 + tx] = lo;
    }
}

__global__ __launch_bounds__(256) void k_prep_agg(
    const float* __restrict__ W1, const float* __restrict__ W2, const float* __restrict__ mem,
    ushort_t* __restrict__ W1T, ushort_t* __restrict__ W2T,
    ushort_t* __restrict__ MThi, ushort_t* __restrict__ MTlo,
    ushort_t* __restrict__ Mhi, ushort_t* __restrict__ Mlo,
    const float* __restrict__ feature, const float* __restrict__ edge_attr,
    const float* __restrict__ ppr, const float* __restrict__ Ws, const float* __restrict__ bs,
    const int* __restrict__ bucket, const int* __restrict__ counts,
    ushort_t* __restrict__ Xbf) {
    int b = blockIdx.x;
    if (b < 600)       { dsplit<false>(W1, W1T, nullptr, XDIM, DHID, b % 24, b / 24); return; }
    else if (b < 1176) { dsplit<false>(W2, W2T, nullptr, DHID, DOUT, (b - 600) % 24, (b - 600) / 24); return; }
    else if (b < 1224) { dsplit<true>(mem, MThi, MTlo, MEMK, DOUT, (b - 1176) % 24, (b - 1176) / 24); return; }
    else if (b < 1416) {
        int i = (b - 1224) * 256 + threadIdx.x;
        if (i < MEMK * 768) {
            ushort_t h, l; split_bf16(mem[i], h, l);
            Mhi[i] = h; Mlo[i] = l;
        }
        return;
    }
    // aggregate role: node n, threads 0..191 active (one float4 over 768 dims)
    int n = b - 1416;
    int t = threadIdx.x;
    if (t >= 192) return;
    const float4* frow = (const float4*)(feature + (size_t)n * DIN);
    float4 acc = frow[t];
    int deg = min(counts[n], BUCKET_CAP);
    const int* bk = bucket + n * BUCKET_CAP;
    for (int j = 0; j < deg; ++j) {
        int e = bk[j];
        float4 v = ((const float4*)(edge_attr + (size_t)e * DIN))[t];
        acc.x += v.x; acc.y += v.y; acc.z += v.z; acc.w += v.w;
    }
    ushort4 h4;
    h4.x = bf_rne(acc.x); h4.y = bf_rne(acc.y);
    h4.z = bf_rne(acc.z); h4.w = bf_rne(acc.w);
    *(ushort4*)(Xbf + (size_t)n * XDIM + t * 4) = h4;
    if (t < DSTRUCT / 4) {
        float p = ppr[n];
        int k = t * 4;
        ushort4 sh;
        sh.x = bf_rne(fmaxf(p * Ws[k+0] + bs[k+0], 0.f));
        sh.y = bf_rne(fmaxf(p * Ws[k+1] + bs[k+1], 0.f));
        sh.z = bf_rne(fmaxf(p * Ws[k+2] + bs[k+2], 0.f));
        sh.w = bf_rne(fmaxf(p * Ws[k+3] + bs[k+3], 0.f));
        *(ushort4*)(Xbf + (size_t)n * XDIM + DIN + k) = sh;
    }
}

// ---------------- single-pass bf16 MFMA GEMM, 128x128 tile (m97 structure) ----------------
#define L_B   4096
#define L_BUF 8192

template<int ACT, int OUTMODE>   // ACT: 0 none, 1 prelu ; OUTMODE: 1 bf16 plane, 2 f32+hi/lo planes
__global__ __launch_bounds__(256) void k_gemm_mfma(
    const ushort_t* __restrict__ A, const ushort_t* __restrict__ B,
    const float* __restrict__ bias, const float* __restrict__ act_p,
    float* __restrict__ Cf, ushort_t* __restrict__ Cbf,
    ushort_t* __restrict__ Chi, ushort_t* __restrict__ Clo,
    int M, int N, int K) {
    __shared__ ushort_t lds[2 * L_BUF];
    int tid = threadIdx.x;
    int l = tid & 63, w = tid >> 6;

    int nbx = N / 128;
    int nwg = nbx * (M / 128);
    int bid = blockIdx.y * nbx + blockIdx.x;
    int q = nwg >> 3;
    int nb = (bid & 7) * q + (bid >> 3);
    int bx = nb % nbx, by = nb / nbx;
    int m0 = by * 128, n0 = bx * 128;

    int wm = w >> 1, wn = w & 1;

    f32x4 acc[4][4];
#pragma unroll
    for (int m = 0; m < 4; ++m)
#pragma unroll
        for (int n = 0; n < 4; ++n) acc[m][n] = (f32x4){0.f, 0.f, 0.f, 0.f};

    int srow = w * 32 + (l >> 2);
    int sc   = (l & 3) * 8;
    const ushort_t* ag0 = A + (size_t)(m0 + srow) * K + sc;
    const ushort_t* ag1 = ag0 + (size_t)16 * K;
    const ushort_t* bg0 = B + (size_t)(n0 + srow) * K + sc;
    const ushort_t* bg1 = bg0 + (size_t)16 * K;

    int NT = K / 32;

    {
        ushort_t* b = lds;
        gld16(ag0, b + w * 1024);
        gld16(ag1, b + w * 1024 + 512);
        gld16(bg0, b + L_B + w * 1024);
        gld16(bg1, b + L_B + w * 1024 + 512);
    }

    int c0 = l >> 4;
    int li = l & 15;

    for (int kt = 0; kt < NT; ++kt) {
        int cur = kt & 1;
        __syncthreads();
        if (kt + 1 < NT) {
            int ko = (kt + 1) * 32;
            ushort_t* b = lds + (cur ^ 1) * L_BUF;
            gld16(ag0 + ko, b + w * 1024);
            gld16(ag1 + ko, b + w * 1024 + 512);
            gld16(bg0 + ko, b + L_B + w * 1024);
            gld16(bg1 + ko, b + L_B + w * 1024 + 512);
        }
        const ushort_t* cb = lds + cur * L_BUF;
        bf16x8 ah[4], bh[4];
#pragma unroll
        for (int m = 0; m < 4; ++m)
            ah[m] = *(const bf16x8*)(cb + (wm * 64 + m * 16 + li) * 32 + c0 * 8);
#pragma unroll
        for (int n = 0; n < 4; ++n)
            bh[n] = *(const bf16x8*)(cb + L_B + (wn * 64 + n * 16 + li) * 32 + c0 * 8);
#pragma unroll
        for (int m = 0; m < 4; ++m)
#pragma unroll
            for (int n = 0; n < 4; ++n)
                acc[m][n] = __builtin_amdgcn_mfma_f32_16x16x32_bf16(ah[m], bh[n], acc[m][n], 0, 0, 0);
    }

    float ap = (ACT == 1) ? *act_p : 0.f;
#pragma unroll
    for (int m = 0; m < 4; ++m)
#pragma unroll
        for (int n = 0; n < 4; ++n) {
            int col = n0 + wn * 64 + n * 16 + li;
            float bv = bias[col];
#pragma unroll
            for (int r = 0; r < 4; ++r) {
                int row = m0 + wm * 64 + m * 16 + c0 * 4 + r;
                float x = acc[m][n][r] + bv;
                if (ACT == 1) x = x > 0.f ? x : ap * x;
                if (OUTMODE == 1) {
                    Cbf[(size_t)row * N + col] = bf_rne(x);
                } else {
                    ushort_t hi, lo; split_bf16(x, hi, lo);
                    Chi[(size_t)row * N + col] = hi;
                    Clo[(size_t)row * N + col] = lo;
                    Cf[(size_t)row * N + col] = x;
                }
            }
        }
}

// ---------------- fused attn (blocks 0..255) + pool (blocks 256..447) ----------------
__global__ __launch_bounds__(256) void k_attn_pool(
    const ushort_t* __restrict__ NFhi, const ushort_t* __restrict__ NFlo,
    const ushort_t* __restrict__ Mhi,  const ushort_t* __restrict__ Mlo,
    const ushort_t* __restrict__ MThi, const ushort_t* __restrict__ MTlo,
    const float* __restrict__ nf, float* __restrict__ re, float* __restrict__ lossac,
    const int* __restrict__ gstart, const int* __restrict__ gend,
    float* __restrict__ gfeatT) {
    if (blockIdx.x >= 256) {
        // pool role: 192 blocks, each (graph g, 256-dim segment)
        int pb = blockIdx.x - 256;
        int g = pb / 3, d = (pb % 3) * 256 + threadIdx.x;
        int s = gstart[g], e = gend[g];
        float a = 0.f;
        for (int n = s; n < e; ++n) a += nf[(size_t)n * DOUT + d];
        gfeatT[(size_t)d * 64 + g] = a / fmaxf((float)(e - s), 1.f);
        return;
    }
    __shared__ ushort_t Ah[96 * 32 * 8];
    __shared__ ushort_t Al[96 * 32 * 8];
    __shared__ ushort_t Wp[2][32 * 64];
    __shared__ float xch[4][32];
    __shared__ float lred[4];
    int tid = threadIdx.x, l = tid & 63, w = tid >> 6;
    int g = l >> 4, li = l & 15;
    int base = blockIdx.x * 32;

    for (int i = w * 12; i < w * 12 + 12; ++i) {
        int kc = i * 2 + (l >> 5), row = l & 31;
        gld16(NFhi + (size_t)(base + row) * 768 + kc * 8, Ah + i * 512);
        gld16(NFlo + (size_t)(base + row) * 768 + kc * 8, Al + i * 512);
    }
    __syncthreads();

    f32x4 sacc[2];
    sacc[0] = (f32x4){0.f,0.f,0.f,0.f}; sacc[1] = (f32x4){0.f,0.f,0.f,0.f};
    int slot = w * 16 + li;
#pragma unroll 4
    for (int kt = 0; kt < 24; ++kt) {
        bf16x8 ah0 = *(const bf16x8*)(Ah + (kt * 4 + g) * 256 + li * 8);
        bf16x8 ah1 = *(const bf16x8*)(Ah + (kt * 4 + g) * 256 + (li + 16) * 8);
        bf16x8 al0 = *(const bf16x8*)(Al + (kt * 4 + g) * 256 + li * 8);
        bf16x8 al1 = *(const bf16x8*)(Al + (kt * 4 + g) * 256 + (li + 16) * 8);
        bf16x8 bh  = *(const bf16x8*)(Mhi + (size_t)slot * 768 + kt * 32 + g * 8);
        bf16x8 bl  = *(const bf16x8*)(Mlo + (size_t)slot * 768 + kt * 32 + g * 8);
        sacc[0] = __builtin_amdgcn_mfma_f32_16x16x32_bf16(ah0, bh, sacc[0], 0, 0, 0);
        sacc[0] = __builtin_amdgcn_mfma_f32_16x16x32_bf16(ah0, bl, sacc[0], 0, 0, 0);
        sacc[0] = __builtin_amdgcn_mfma_f32_16x16x32_bf16(al0, bh, sacc[0], 0, 0, 0);
        sacc[1] = __builtin_amdgcn_mfma_f32_16x16x32_bf16(ah1, bh, sacc[1], 0, 0, 0);
        sacc[1] = __builtin_amdgcn_mfma_f32_16x16x32_bf16(ah1, bl, sacc[1], 0, 0, 0);
        sacc[1] = __builtin_amdgcn_mfma_f32_16x16x32_bf16(al1, bh, sacc[1], 0, 0, 0);
    }

    float mxv[8];
#pragma unroll
    for (int m = 0; m < 2; ++m)
#pragma unroll
        for (int r = 0; r < 4; ++r) {
            float v = sacc[m][r];
            v = fmaxf(v, __shfl_xor(v, 1)); v = fmaxf(v, __shfl_xor(v, 2));
            v = fmaxf(v, __shfl_xor(v, 4)); v = fmaxf(v, __shfl_xor(v, 8));
            mxv[m * 4 + r] = v;
        }
    if (li == 0) {
#pragma unroll
        for (int m = 0; m < 2; ++m)
#pragma unroll
            for (int r = 0; r < 4; ++r) xch[w][m * 16 + g * 4 + r] = mxv[m * 4 + r];
    }
    __syncthreads();
    float ev[8], sv[8];
#pragma unroll
    for (int m = 0; m < 2; ++m)
#pragma unroll
        for (int r = 0; r < 4; ++r) {
            int row = m * 16 + g * 4 + r;
            float mx = fmaxf(fmaxf(xch[0][row], xch[1][row]), fmaxf(xch[2][row], xch[3][row]));
            float e = __expf(sacc[m][r] - mx);
            ev[m * 4 + r] = e;
            float s = e;
            s += __shfl_xor(s, 1); s += __shfl_xor(s, 2);
            s += __shfl_xor(s, 4); s += __shfl_xor(s, 8);
            sv[m * 4 + r] = s;
        }
    __syncthreads();
    if (li == 0) {
#pragma unroll
        for (int m = 0; m < 2; ++m)
#pragma unroll
            for (int r = 0; r < 4; ++r) xch[w][m * 16 + g * 4 + r] = sv[m * 4 + r];
    }
    __syncthreads();
#pragma unroll
    for (int m = 0; m < 2; ++m)
#pragma unroll
        for (int r = 0; r < 4; ++r) {
            int row = m * 16 + g * 4 + r;
            float tot = xch[0][row] + xch[1][row] + xch[2][row] + xch[3][row];
            float wv = ev[m * 4 + r] / tot;
            ushort_t hi, lo; split_bf16(wv, hi, lo);
            int idx = row * 64 + (slot ^ ((row & 7) << 3));
            Wp[0][idx] = hi; Wp[1][idx] = lo;
        }
    __syncthreads();

    bf16x8 wah[2][2], wal[2][2];
#pragma unroll
    for (int m = 0; m < 2; ++m)
#pragma unroll
        for (int kt2 = 0; kt2 < 2; ++kt2) {
            int row = m * 16 + li;
            int k8 = kt2 * 4 + g;
            int idx = row * 64 + ((k8 * 8) ^ ((row & 7) << 3));
            wah[m][kt2] = *(const bf16x8*)&Wp[0][idx];
            wal[m][kt2] = *(const bf16x8*)&Wp[1][idx];
        }
    float lp = 0.f;
#pragma unroll 2
    for (int nfi = 0; nfi < 12; ++nfi) {
        int col = w * 192 + nfi * 16 + li;
        f32x4 pacc[2];
        pacc[0] = (f32x4){0.f,0.f,0.f,0.f}; pacc[1] = (f32x4){0.f,0.f,0.f,0.f};
#pragma unroll
        for (int kt2 = 0; kt2 < 2; ++kt2) {
            bf16x8 bh = *(const bf16x8*)(MThi + (size_t)col * 64 + kt2 * 32 + g * 8);
            bf16x8 bl = *(const bf16x8*)(MTlo + (size_t)col * 64 + kt2 * 32 + g * 8);
#pragma unroll
            for (int m = 0; m < 2; ++m) {
                pacc[m] = __builtin_amdgcn_mfma_f32_16x16x32_bf16(wah[m][kt2], bh, pacc[m], 0, 0, 0);
                pacc[m] = __builtin_amdgcn_mfma_f32_16x16x32_bf16(wah[m][kt2], bl, pacc[m], 0, 0, 0);
                pacc[m] = __builtin_amdgcn_mfma_f32_16x16x32_bf16(wal[m][kt2], bh, pacc[m], 0, 0, 0);
            }
        }
#pragma unroll
        for (int m = 0; m < 2; ++m)
#pragma unroll
            for (int r = 0; r < 4; ++r) {
                int row = base + m * 16 + g * 4 + r;
                float v = pacc[m][r] * (1.f / 64.f);
                float x = nf[(size_t)row * 768 + col];
                re[(size_t)row * 768 + col] = v;
                float d = x - v;
                lp = fmaf(d, d, lp);
            }
    }
    for (int o = 32; o; o >>= 1) lp += __shfl_xor(lp, o);
    if (l == 0) lred[w] = lp;
    __syncthreads();
    if (tid == 0) atomicAdd(lossac, lred[0] + lred[1] + lred[2] + lred[3]);
}

// ---------------- pooled MLP, transpose-fed ----------------
template<int ACT>   // 2: tanh, write OutT[n][m] ; 0: none, write OutR[m][n]
__global__ __launch_bounds__(256) void k_mlp_t(const float* __restrict__ AT, const float* __restrict__ B,
                                               const float* __restrict__ bias,
                                               float* __restrict__ OutT, float* __restrict__ OutR) {
    __shared__ float red[4][64];
    int n = blockIdx.x;
    int l = threadIdx.x & 63, qw = threadIdx.x >> 6;
    float s = 0.f;
    const float* a = AT + l;
    const float* b = B + n;
#pragma unroll 8
    for (int k = qw * 192; k < qw * 192 + 192; ++k)
        s = fmaf(a[k * 64], b[k * 768], s);
    red[qw][l] = s;
    __syncthreads();
    if (threadIdx.x < 64) {
        float v = red[0][l] + red[1][l] + red[2][l] + red[3][l] + bias[n];
        if (ACT == 2) { v = tanhf(v); OutT[n * 64 + l] = v; }
        else OutR[(size_t)l * 768 + n] = v;
    }
}

__global__ void k_loss_final(const float* __restrict__ acc, float* __restrict__ out, float invn) {
    if (threadIdx.x == 0 && blockIdx.x == 0) out[0] = acc[0] * invn;
}

// ---------------- launch ----------------
extern "C" void kernel_launch(void* const* d_in, const int* in_sizes, int n_in,
                              void* d_out, int out_size, void* d_ws, size_t ws_size,
                              hipStream_t stream) {
    const float* feature  = (const float*)d_in[0];
    const float* ppr      = (const float*)d_in[1];
    const float* edge_attr= (const float*)d_in[2];
    const float* Ws       = (const float*)d_in[3];
    const float* bs       = (const float*)d_in[4];
    const float* W1       = (const float*)d_in[5];
    const float* b1       = (const float*)d_in[6];
    const float* prelu_a  = (const float*)d_in[7];
    const float* W2       = (const float*)d_in[8];
    const float* b2       = (const float*)d_in[9];
    const float* Wp1      = (const float*)d_in[10];
    const float* bp1      = (const float*)d_in[11];
    const float* Wp2      = (const float*)d_in[12];
    const float* bp2      = (const float*)d_in[13];
    const float* memory   = (const float*)d_in[14];
    const int*   edge_index = (const int*)d_in[15];
    const int*   batch_ids  = (const int*)d_in[16];

    const int E = in_sizes[15] / 2;
    const int N = in_sizes[0] / DIN;
    const int* col = edge_index + E;

    char* ws = (char*)d_ws;
    ushort_t* Xbf  = (ushort_t*)(ws + OFF_XBF);
    ushort_t* Hbf  = (ushort_t*)(ws + OFF_HBF);
    float*    nf   = (float*)   (ws + OFF_NF);
    ushort_t* NFhi = (ushort_t*)(ws + OFF_NFHI);
    ushort_t* NFlo = (ushort_t*)(ws + OFF_NFLO);
    ushort_t* W1T  = (ushort_t*)(ws + OFF_W1T);
    ushort_t* W2T  = (ushort_t*)(ws + OFF_W2T);
    ushort_t* Mhi  = (ushort_t*)(ws + OFF_MHI);
    ushort_t* Mlo  = (ushort_t*)(ws + OFF_MLO);
    ushort_t* MThi = (ushort_t*)(ws + OFF_MTHI);
    ushort_t* MTlo = (ushort_t*)(ws + OFF_MTLO);
    int*   bucket = (int*)(ws + OFF_BUCKET);
    int*   counts = (int*)(ws + OFF_COUNTS);
    int*   gstart = (int*)(ws + OFF_GSTART);
    int*   gend   = (int*)(ws + OFF_GEND);
    float* lossac = (float*)(ws + OFF_LOSS);
    float* gfeatT = (float*)(ws + OFF_GFEAT);
    float* t1T    = (float*)(ws + OFF_T1);

    float* out_pooled = (float*)d_out;
    float* out_re     = (float*)d_out + NGRAPH * DOUT;
    float* out_loss   = (float*)d_out + NGRAPH * DOUT + (size_t)N * DOUT;

    (void)hipMemsetAsync(ws + ZERO_OFF, 0, ZERO_BYTES, stream);

    k_csr<<<1024 + (NNODES + 255) / 256, 256, 0, stream>>>(
        col, counts, bucket, E, batch_ids, gstart, gend, N);

    k_prep_agg<<<1416 + N, 256, 0, stream>>>(
        W1, W2, memory, W1T, W2T, MThi, MTlo, Mhi, Mlo,
        feature, edge_attr, ppr, Ws, bs, bucket, counts, Xbf);

    k_gemm_mfma<1, 1><<<dim3(DHID / 128, N / 128), 256, 0, stream>>>(
        Xbf, W1T, b1, prelu_a, nullptr, Hbf, nullptr, nullptr, N, DHID, XDIM);
    k_gemm_mfma<0, 2><<<dim3(DOUT / 128, N / 128), 256, 0, stream>>>(
        Hbf, W2T, b2, nullptr, nf, nullptr, NFhi, NFlo, N, DOUT, DHID);

    k_attn_pool<<<256 + 192, 256, 0, stream>>>(
        NFhi, NFlo, Mhi, Mlo, MThi, MTlo, nf, out_re, lossac, gstart, gend, gfeatT);

    k_mlp_t<2><<<768, 256, 0, stream>>>(gfeatT, Wp1, bp1, t1T, nullptr);
    k_mlp_t<0><<<768, 256, 0, stream>>>(t1T, Wp2, bp2, nullptr, out_pooled);

    k_loss_final<<<1, 64, 0, stream>>>(lossac, out_loss, 1.f / (float)((size_t)N * DOUT));
}